// Round 2
// baseline (671.335 us; speedup 1.0000x reference)
//
#include <hip/hip_runtime.h>
#include <hip/hip_bf16.h>

typedef __hip_bfloat16 bf16;
typedef __attribute__((ext_vector_type(4))) float f32x4;
typedef __attribute__((ext_vector_type(8))) short s16x8;

#define DEV static __device__ __forceinline__

namespace {

constexpr float kEPS = 1e-5f;
constexpr float kFACTOR = 1.0f / 112.0f;  // 1/sqrt(196*64)

DEV float hswish_f(float v) { return v * fminf(fmaxf(v + 3.f, 0.f), 6.f) * (1.f / 6.f); }
DEV float blo(unsigned r) { return __uint_as_float(r << 16); }
DEV float bhi(unsigned r) { return __uint_as_float(r & 0xFFFF0000u); }

// ---- K0: convert pointwise weights fp32 -> bf16 (+ reorder G to c*8+h rows,
//          precompute bn2 scale/shift in storage order) ---------------------
__global__ void cvt_pw_kernel(const float* __restrict__ a,
                              const float* __restrict__ b,
                              const float* __restrict__ cG,
                              const float* __restrict__ g2g, const float* __restrict__ g2b,
                              const float* __restrict__ g2m, const float* __restrict__ g2v,
                              bf16* __restrict__ oa, bf16* __restrict__ ob,
                              bf16* __restrict__ oc, float* __restrict__ bnscl,
                              float* __restrict__ bnsft) {
  int i = blockIdx.x * 256 + threadIdx.x;
  if (i < 512 * 256) {
    oa[i] = __float2bfloat16(a[i]);
    ob[i] = __float2bfloat16(b[i]);
  }
  if (i < 2048 * 256) {
    int r = i >> 8, k = i & 255;          // ref row r = h*256+c
    int h = r >> 8, c = r & 255;
    oc[(c * 8 + h) * 256 + k] = __float2bfloat16(cG[i]);
  }
  if (i < 2048) {                         // storage o = c*8+h
    int c = i >> 3, h = i & 7, ref = h * 256 + c;
    float s = g2g[ref] * rsqrtf(g2v[ref] + kEPS);
    bnscl[i] = s;
    bnsft[i] = g2b[ref] - g2m[ref] * s;
  }
}

// ---- K1: depthwise conv(1,3,3)+BN+hswish, 3 branches ---------------------
// writes h[n][t*196+s][c] bf16 (c contiguous -> GEMM K-contiguous)
__global__ __launch_bounds__(256) void conv_kernel(
    const float* __restrict__ x,
    const float* __restrict__ tdw, const float* __restrict__ tg,
    const float* __restrict__ tb, const float* __restrict__ tm, const float* __restrict__ tv,
    const float* __restrict__ pdw, const float* __restrict__ pg,
    const float* __restrict__ pb, const float* __restrict__ pm, const float* __restrict__ pv,
    const float* __restrict__ gdw, const float* __restrict__ gG,
    const float* __restrict__ gb, const float* __restrict__ gm, const float* __restrict__ gv,
    bf16* __restrict__ h_t, bf16* __restrict__ h_p, bf16* __restrict__ h_g) {
  int bid = blockIdx.x;
  int cb = bid & 3, t = (bid >> 2) & 15, n = bid >> 6;
  int c0 = cb * 64;
  __shared__ float xs[64][197];
  __shared__ float wts[3][64][9];
  __shared__ float sc[3][64], sh[3][64];
  int tid = threadIdx.x;
  for (int i = tid; i < 64 * 9; i += 256) {
    int cl = i / 9, k = i % 9;
    wts[0][cl][k] = tdw[(c0 + cl) * 9 + k];
    wts[1][cl][k] = pdw[(c0 + cl) * 9 + k];
    wts[2][cl][k] = gdw[(c0 + cl) * 9 + k];
  }
  if (tid < 64) {
    int c = c0 + tid;
    float s0 = tg[c] * rsqrtf(tv[c] + kEPS);
    sc[0][tid] = s0; sh[0][tid] = tb[c] - tm[c] * s0;
    float s1 = pg[c] * rsqrtf(pv[c] + kEPS);
    sc[1][tid] = s1; sh[1][tid] = pb[c] - pm[c] * s1;
    float s2 = gG[c] * rsqrtf(gv[c] + kEPS);
    sc[2][tid] = s2; sh[2][tid] = gb[c] - gm[c] * s2;
  }
  const float* xb = x + ((size_t)(n * 256 + c0) * 16 + t) * 196;
  for (int i = tid; i < 64 * 196; i += 256) {
    int cl = i / 196, s = i % 196;
    xs[cl][s] = xb[(size_t)cl * 3136 + s];
  }
  __syncthreads();
  for (int i = tid; i < 64 * 196; i += 256) {
    int cl = i & 63, sp = i >> 6;
    int hs = sp / 14, wsp = sp % 14;
    float a0 = 0.f, a1 = 0.f, a2 = 0.f;
    #pragma unroll
    for (int dy = -1; dy <= 1; ++dy) {
      int yy = hs + dy;
      if (yy < 0 || yy >= 14) continue;
      #pragma unroll
      for (int dx = -1; dx <= 1; ++dx) {
        int xx = wsp + dx;
        if (xx < 0 || xx >= 14) continue;
        float v = xs[cl][yy * 14 + xx];
        int k = (dy + 1) * 3 + (dx + 1);
        a0 = fmaf(wts[0][cl][k], v, a0);
        a1 = fmaf(wts[1][cl][k], v, a1);
        a2 = fmaf(wts[2][cl][k], v, a2);
      }
    }
    a0 = hswish_f(a0 * sc[0][cl] + sh[0][cl]);
    a1 = hswish_f(a1 * sc[1][cl] + sh[1][cl]);
    a2 = hswish_f(a2 * sc[2][cl] + sh[2][cl]);
    size_t oidx = ((size_t)n * 3136 + t * 196 + sp) * 256 + c0 + cl;
    h_t[oidx] = __float2bfloat16(a0);
    h_p[oidx] = __float2bfloat16(a1);
    h_g[oidx] = __float2bfloat16(a2);
  }
}

// ---- K2a: bf16 MFMA GEMM  D[n][o][ts] = sum_c W[o][c]*H[ts][c] + bias ----
// (theta/phi: keeps o-major layout that adj_accum wants)
__global__ __launch_bounds__(256) void gemm_op_kernel(
    const bf16* __restrict__ A,  // W [512][256]
    const bf16* __restrict__ B,  // H [8][3136][256]
    bf16* __restrict__ D,        // [8][512][3136]
    const float* __restrict__ bias) {
  int mt = blockIdx.x, nt = blockIdx.y, n = blockIdx.z;
  __shared__ __align__(16) bf16 lds_a[128 * 64];
  __shared__ __align__(16) bf16 lds_b[64 * 64];
  int tid = threadIdx.x;
  int wid = tid >> 6, lane = tid & 63;
  int wr = wid >> 1, wc = wid & 1;
  int l15 = lane & 15, lh = lane >> 4;
  f32x4 acc[4][2];
  #pragma unroll
  for (int m = 0; m < 4; ++m)
    #pragma unroll
    for (int q = 0; q < 2; ++q) acc[m][q] = (f32x4){0.f, 0.f, 0.f, 0.f};
  const bf16* Ab = A + (size_t)mt * 128 * 256;
  const bf16* Bb = B + ((size_t)n * 3136 + (size_t)nt * 64) * 256;
  for (int k0 = 0; k0 < 256; k0 += 64) {
    #pragma unroll
    for (int it = 0; it < 4; ++it) {
      int g = tid + it * 256;
      int row = g >> 3, c16 = g & 7;
      int4 v = *(const int4*)(Ab + (size_t)row * 256 + k0 + c16 * 8);
      *(int4*)((char*)lds_a + row * 128 + ((c16 * 16) ^ ((row & 7) << 4))) = v;
    }
    #pragma unroll
    for (int it = 0; it < 2; ++it) {
      int g = tid + it * 256;
      int row = g >> 3, c16 = g & 7;
      int4 v = *(const int4*)(Bb + (size_t)row * 256 + k0 + c16 * 8);
      *(int4*)((char*)lds_b + row * 128 + ((c16 * 16) ^ ((row & 7) << 4))) = v;
    }
    __syncthreads();
    #pragma unroll
    for (int kk = 0; kk < 64; kk += 32) {
      s16x8 af[4], bfr[2];
      #pragma unroll
      for (int m = 0; m < 4; ++m) {
        int row = wr * 64 + m * 16 + l15;
        af[m] = *(const s16x8*)((const char*)lds_a + row * 128 +
                                (((kk + lh * 8) * 2) ^ ((row & 7) << 4)));
      }
      #pragma unroll
      for (int q = 0; q < 2; ++q) {
        int row = wc * 32 + q * 16 + l15;
        bfr[q] = *(const s16x8*)((const char*)lds_b + row * 128 +
                                 (((kk + lh * 8) * 2) ^ ((row & 7) << 4)));
      }
      #pragma unroll
      for (int m = 0; m < 4; ++m)
        #pragma unroll
        for (int q = 0; q < 2; ++q)
          acc[m][q] = __builtin_amdgcn_mfma_f32_16x16x32_bf16(af[m], bfr[q], acc[m][q], 0, 0, 0);
    }
    __syncthreads();
  }
  #pragma unroll
  for (int m = 0; m < 4; ++m) {
    #pragma unroll
    for (int q = 0; q < 2; ++q) {
      int col = nt * 64 + wc * 32 + q * 16 + l15;
      #pragma unroll
      for (int r = 0; r < 4; ++r) {
        int orow = mt * 128 + wr * 64 + m * 16 + lh * 4 + r;
        float v = acc[m][q][r] + bias[orow];
        D[((size_t)n * 512 + orow) * 3136 + col] = __float2bfloat16(v);
      }
    }
  }
}

// ---- K2b: transposed-output GEMM for g-branch ----------------------------
// D[n][ts][o] = bn2+hswish( sum_c H[ts][c] * W[o][c] ), o = c_out*8+h storage
__global__ __launch_bounds__(256) void gemm_g_kernel(
    const bf16* __restrict__ A,   // hG [8][3136][256] (M = ts rows)
    const bf16* __restrict__ W,   // pwG [2048][256]   (N = o rows, storage order)
    bf16* __restrict__ D,         // gg [8][3136][2048]
    const float* __restrict__ bnscl, const float* __restrict__ bnsft) {
  int tsb = blockIdx.x, otb = blockIdx.y, n = blockIdx.z;
  __shared__ __align__(16) bf16 lds_a[64 * 64];
  __shared__ __align__(16) bf16 lds_b[128 * 64];
  int tid = threadIdx.x;
  int wid = tid >> 6, lane = tid & 63;
  int wr = wid >> 1, wc = wid & 1;
  int l15 = lane & 15, lh = lane >> 4;
  f32x4 acc[2][4];
  #pragma unroll
  for (int m = 0; m < 2; ++m)
    #pragma unroll
    for (int q = 0; q < 4; ++q) acc[m][q] = (f32x4){0.f, 0.f, 0.f, 0.f};
  const bf16* Ab = A + ((size_t)n * 3136 + (size_t)tsb * 64) * 256;
  const bf16* Wb = W + (size_t)otb * 128 * 256;
  for (int k0 = 0; k0 < 256; k0 += 64) {
    #pragma unroll
    for (int it = 0; it < 2; ++it) {
      int g = tid + it * 256;            // A: 64 rows x 8 granules
      int row = g >> 3, c16 = g & 7;
      int4 v = *(const int4*)(Ab + (size_t)row * 256 + k0 + c16 * 8);
      *(int4*)((char*)lds_a + row * 128 + ((c16 * 16) ^ ((row & 7) << 4))) = v;
    }
    #pragma unroll
    for (int it = 0; it < 4; ++it) {
      int g = tid + it * 256;            // B: 128 rows x 8 granules
      int row = g >> 3, c16 = g & 7;
      int4 v = *(const int4*)(Wb + (size_t)row * 256 + k0 + c16 * 8);
      *(int4*)((char*)lds_b + row * 128 + ((c16 * 16) ^ ((row & 7) << 4))) = v;
    }
    __syncthreads();
    #pragma unroll
    for (int kk = 0; kk < 64; kk += 32) {
      s16x8 af[2], bfr[4];
      #pragma unroll
      for (int m = 0; m < 2; ++m) {
        int row = wr * 32 + m * 16 + l15;
        af[m] = *(const s16x8*)((const char*)lds_a + row * 128 +
                                (((kk + lh * 8) * 2) ^ ((row & 7) << 4)));
      }
      #pragma unroll
      for (int q = 0; q < 4; ++q) {
        int row = wc * 64 + q * 16 + l15;
        bfr[q] = *(const s16x8*)((const char*)lds_b + row * 128 +
                                 (((kk + lh * 8) * 2) ^ ((row & 7) << 4)));
      }
      #pragma unroll
      for (int m = 0; m < 2; ++m)
        #pragma unroll
        for (int q = 0; q < 4; ++q)
          acc[m][q] = __builtin_amdgcn_mfma_f32_16x16x32_bf16(af[m], bfr[q], acc[m][q], 0, 0, 0);
    }
    __syncthreads();
  }
  #pragma unroll
  for (int q = 0; q < 4; ++q) {
    int ocol = otb * 128 + wc * 64 + q * 16 + l15;
    float scl = bnscl[ocol], sft = bnsft[ocol];
    #pragma unroll
    for (int m = 0; m < 2; ++m) {
      #pragma unroll
      for (int r = 0; r < 4; ++r) {
        int tsrow = tsb * 64 + wr * 32 + m * 16 + lh * 4 + r;
        float v = hswish_f(acc[m][q][r] * scl + sft);
        D[((size_t)n * 3136 + tsrow) * 2048 + ocol] = __float2bfloat16(v);
      }
    }
  }
}

// ---- K3: adjacency logits, partial over e-blocks (atomicAdd) -------------
__global__ __launch_bounds__(256) void adj_accum_kernel(const bf16* __restrict__ th,
                                                        const bf16* __restrict__ ph,
                                                        float* __restrict__ adj_raw) {
  int bid = blockIdx.x;
  int eb = bid & 7, h = (bid >> 3) & 7, n = bid >> 6;
  __shared__ __align__(16) float As[16 * 196];
  __shared__ __align__(16) float Bs[16 * 196];
  int tid = threadIdx.x;
  int t = tid >> 4, u = tid & 15;
  float acc = 0.f;
  for (int e8 = 0; e8 < 8; ++e8) {
    int e = eb * 8 + e8;
    const bf16* tp = th + ((size_t)n * 512 + h * 64 + e) * 3136;
    const bf16* pp = ph + ((size_t)n * 512 + h * 64 + e) * 3136;
    __syncthreads();
    for (int i = tid; i < 3136; i += 256) {
      As[i] = __bfloat162float(tp[i]);
      Bs[i] = __bfloat162float(pp[i]);
    }
    __syncthreads();
    const float* ar = As + t * 196;
    const float* br = Bs + u * 196;
    #pragma unroll
    for (int j = 0; j < 49; ++j) {
      f32x4 a = *(const f32x4*)(ar + j * 4);
      f32x4 b = *(const f32x4*)(br + j * 4);
      acc = fmaf(a[0], b[0], acc); acc = fmaf(a[1], b[1], acc);
      acc = fmaf(a[2], b[2], acc); acc = fmaf(a[3], b[3], acc);
    }
  }
  atomicAdd(&adj_raw[((n * 8 + h) * 16 + t) * 16 + u], acc);
}

// ---- K3b: softmax over u (16), with FACTOR -------------------------------
__global__ void adj_softmax_kernel(const float* __restrict__ raw, float* __restrict__ adj) {
  int r = blockIdx.x * 256 + threadIdx.x;
  if (r >= 1024) return;
  const float* p = raw + r * 16;
  float* q = adj + r * 16;
  float v[16], mx = -1e30f;
  #pragma unroll
  for (int u = 0; u < 16; ++u) { v[u] = p[u] * kFACTOR; mx = fmaxf(mx, v[u]); }
  float s = 0.f;
  #pragma unroll
  for (int u = 0; u < 16; ++u) { v[u] = __expf(v[u] - mx); s += v[u]; }
  float inv = 1.f / s;
  #pragma unroll
  for (int u = 0; u < 16; ++u) q[u] = v[u] * inv;
}

// ---- K4: hf[n][t][h] partial sums over (c,s) -----------------------------
// gg layout [n][u*196+s][o=c*8+h]; block = (sb, hp) via x, n via z.
// adj reads are block-uniform -> scalar loads (K$), no LDS.
__global__ __launch_bounds__(256) void hf_kernel(const bf16* __restrict__ gg,
                                                 const float* __restrict__ adj,
                                                 float* __restrict__ hf) {
  int hp = blockIdx.x & 3, sb = blockIdx.x >> 2;
  int n = blockIdx.z;
  int c = threadIdx.x;
  int h0 = hp * 2;
  const float* a0 = adj + n * 2048 + h0 * 256;   // [t*16+u]
  const float* a1 = a0 + 256;
  const bf16* gbase = gg + (size_t)n * 3136 * 2048 + (size_t)c * 8 + h0;
  float hacc0[16], hacc1[16];
  #pragma unroll
  for (int t = 0; t < 16; ++t) { hacc0[t] = 0.f; hacc1[t] = 0.f; }
  for (int s4 = 0; s4 < 4; ++s4) {
    int s = sb * 4 + s4;
    const bf16* gp = gbase + (size_t)s * 2048;
    float gv0[16], gv1[16];
    #pragma unroll
    for (int u = 0; u < 16; ++u) {
      unsigned raw = *(const unsigned*)(gp + (size_t)u * 196 * 2048);
      gv0[u] = blo(raw);
      gv1[u] = bhi(raw);
    }
    #pragma unroll
    for (int t = 0; t < 16; ++t) {
      float z0 = 0.f, z1 = 0.f;
      #pragma unroll
      for (int u = 0; u < 16; ++u) {
        z0 = fmaf(a0[t * 16 + u], gv0[u], z0);
        z1 = fmaf(a1[t * 16 + u], gv1[u], z1);
      }
      hacc0[t] += hswish_f(z0);
      hacc1[t] += hswish_f(z1);
    }
  }
  #pragma unroll
  for (int t = 0; t < 16; ++t) {
    float v0 = hacc0[t], v1 = hacc1[t];
    #pragma unroll
    for (int off = 32; off; off >>= 1) {
      v0 += __shfl_xor(v0, off);
      v1 += __shfl_xor(v1, off);
    }
    if ((threadIdx.x & 63) == 0) {
      atomicAdd(&hf[(n * 16 + t) * 8 + h0], v0);
      atomicAdd(&hf[(n * 16 + t) * 8 + h0 + 1], v1);
    }
  }
}

// ---- K5: head-mix attn = softmax(hf_mean @ heads_w) ----------------------
__global__ void attn_kernel(const float* __restrict__ hf, const float* __restrict__ hw,
                            float* __restrict__ attn) {
  int tid = threadIdx.x;
  if (tid >= 128) return;
  int n = tid >> 4, t = tid & 15;
  const float inv = 1.0f / (256.0f * 196.0f);
  float hm[8];
  #pragma unroll
  for (int h = 0; h < 8; ++h) hm[h] = hf[(n * 16 + t) * 8 + h] * inv;
  float o[8], mx = -1e30f;
  #pragma unroll
  for (int h2 = 0; h2 < 8; ++h2) {
    float s = 0.f;
    #pragma unroll
    for (int h = 0; h < 8; ++h) s = fmaf(hm[h], hw[h * 8 + h2], s);
    o[h2] = s; mx = fmaxf(mx, s);
  }
  float s = 0.f;
  #pragma unroll
  for (int h2 = 0; h2 < 8; ++h2) { o[h2] = __expf(o[h2] - mx); s += o[h2]; }
  float is = 1.f / s;
  #pragma unroll
  for (int h2 = 0; h2 < 8; ++h2) attn[(n * 16 + t) * 8 + h2] = o[h2] * is;
}

// ---- K6: z[n][ts][c] = sum_h attn * hswish(sum_u adj*gg) -----------------
// thread = c (owns all 8 h in two short4 halves); adj/attn block-uniform.
__global__ __launch_bounds__(256) void out_compute_kernel(const bf16* __restrict__ gg,
                                                          const float* __restrict__ adj,
                                                          const float* __restrict__ attn,
                                                          bf16* __restrict__ ztmp) {
  int s = blockIdx.x, n = blockIdx.y;
  int c = threadIdx.x;
  const float* ap = adj + n * 2048;       // [h*256 + t*16 + u]
  const float* at = attn + n * 128;       // [t*8 + h]
  float zout[16];
  #pragma unroll
  for (int t = 0; t < 16; ++t) zout[t] = 0.f;
  #pragma unroll
  for (int hh = 0; hh < 2; ++hh) {
    const bf16* gp = gg + (size_t)n * 3136 * 2048 + (size_t)s * 2048 + c * 8 + hh * 4;
    float gv[16][4];
    #pragma unroll
    for (int u = 0; u < 16; ++u) {
      uint2 raw = *(const uint2*)(gp + (size_t)u * 196 * 2048);
      gv[u][0] = blo(raw.x); gv[u][1] = bhi(raw.x);
      gv[u][2] = blo(raw.y); gv[u][3] = bhi(raw.y);
    }
    #pragma unroll
    for (int t = 0; t < 16; ++t) {
      #pragma unroll
      for (int j = 0; j < 4; ++j) {
        int h = hh * 4 + j;
        const float* ar = ap + h * 256 + t * 16;
        float z = 0.f;
        #pragma unroll
        for (int u = 0; u < 16; ++u) z = fmaf(ar[u], gv[u][j], z);
        zout[t] = fmaf(at[t * 8 + h], hswish_f(z), zout[t]);
      }
    }
  }
  #pragma unroll
  for (int t = 0; t < 16; ++t)
    ztmp[((size_t)n * 3136 + t * 196 + s) * 256 + c] = __float2bfloat16(zout[t]);
}

// ---- K7: transpose z [ts][c]->[c][ts], add residual, final hswish --------
__global__ __launch_bounds__(256) void zres_kernel(const bf16* __restrict__ ztmp,
                                                   const float* __restrict__ x,
                                                   float* __restrict__ out) {
  int tsb = blockIdx.x, cb = blockIdx.y, n = blockIdx.z;
  __shared__ __align__(16) bf16 tile[64 * 64];  // [ts][c], XOR-swizzled rows
  int tid = threadIdx.x;
  #pragma unroll
  for (int it = 0; it < 2; ++it) {
    int g = tid + it * 256;
    int row = g >> 3, cq = g & 7;
    int4 v = *(const int4*)(ztmp + ((size_t)n * 3136 + tsb * 64 + row) * 256 + cb * 64 + cq * 8);
    *(int4*)((char*)tile + row * 128 + ((cq * 16) ^ ((row & 7) << 4))) = v;
  }
  __syncthreads();
  int cl = tid & 63, tq = tid >> 6;
  size_t obase = ((size_t)(n * 256 + cb * 64 + cl)) * 3136 + tsb * 64 + tq * 16;
  #pragma unroll
  for (int i = 0; i < 16; i += 4) {
    f32x4 xv = *(const f32x4*)(x + obase + i);
    f32x4 r;
    #pragma unroll
    for (int j = 0; j < 4; ++j) {
      int row = tq * 16 + i + j;
      unsigned short zb = *(const unsigned short*)((const char*)tile + row * 128 +
                                                   ((cl * 2) ^ ((row & 7) << 4)));
      float z = __uint_as_float((unsigned)zb << 16);
      r[j] = hswish_f(xv[j] + z);
    }
    *(f32x4*)(out + obase + i) = r;
  }
}

}  // namespace

extern "C" void kernel_launch(void* const* d_in, const int* in_sizes, int n_in,
                              void* d_out, int out_size, void* d_ws, size_t ws_size,
                              hipStream_t stream) {
  const float* x       = (const float*)d_in[0];
  const float* t_dw    = (const float*)d_in[1];
  const float* t_g     = (const float*)d_in[2];
  const float* t_b     = (const float*)d_in[3];
  const float* t_m     = (const float*)d_in[4];
  const float* t_v     = (const float*)d_in[5];
  const float* t_pw    = (const float*)d_in[6];
  const float* p_dw    = (const float*)d_in[7];
  const float* p_g     = (const float*)d_in[8];
  const float* p_b     = (const float*)d_in[9];
  const float* p_m     = (const float*)d_in[10];
  const float* p_v     = (const float*)d_in[11];
  const float* p_pw    = (const float*)d_in[12];
  const float* g_dw    = (const float*)d_in[13];
  const float* g_g     = (const float*)d_in[14];
  const float* g_b     = (const float*)d_in[15];
  const float* g_m     = (const float*)d_in[16];
  const float* g_v     = (const float*)d_in[17];
  const float* g_pw    = (const float*)d_in[18];
  const float* t_pb    = (const float*)d_in[19];
  const float* p_pb    = (const float*)d_in[20];
  const float* g2_g    = (const float*)d_in[21];
  const float* g2_b    = (const float*)d_in[22];
  const float* g2_m    = (const float*)d_in[23];
  const float* g2_v    = (const float*)d_in[24];
  const float* heads_w = (const float*)d_in[25];
  float* out = (float*)d_out;
  (void)in_sizes; (void)n_in; (void)out_size; (void)ws_size;

  char* w = (char*)d_ws;
  size_t off = 0;
  auto take = [&](size_t bytes) {
    char* p = w + off;
    off = (off + bytes + 255) & ~(size_t)255;
    return p;
  };
  bf16* pwT = (bf16*)take(512 * 256 * 2);
  bf16* pwP = (bf16*)take(512 * 256 * 2);
  bf16* pwG = (bf16*)take(2048 * 256 * 2);
  float* bnscl = (float*)take(2048 * 4);
  float* bnsft = (float*)take(2048 * 4);
  bf16* hT  = (bf16*)take((size_t)8 * 3136 * 256 * 2);
  bf16* hP  = (bf16*)take((size_t)8 * 3136 * 256 * 2);
  bf16* hG  = (bf16*)take((size_t)8 * 3136 * 256 * 2);
  bf16* th  = (bf16*)take((size_t)8 * 512 * 3136 * 2);
  bf16* ph  = (bf16*)take((size_t)8 * 512 * 3136 * 2);
  bf16* gg  = (bf16*)take((size_t)8 * 3136 * 2048 * 2);
  float* adj_raw = (float*)take(1024 * 16 * 4);
  float* adj     = (float*)take(1024 * 16 * 4);
  float* hf      = (float*)take(1024 * 4);
  float* attn    = (float*)take(1024 * 4);
  bf16* ztmp = hT;  // hT is dead after its GEMM; reuse for z (same size)

  hipMemsetAsync(adj_raw, 0, 1024 * 16 * 4, stream);
  hipMemsetAsync(hf, 0, 1024 * 4, stream);

  cvt_pw_kernel<<<2048, 256, 0, stream>>>(t_pw, p_pw, g_pw, g2_g, g2_b, g2_m, g2_v,
                                          pwT, pwP, pwG, bnscl, bnsft);
  conv_kernel<<<512, 256, 0, stream>>>(x, t_dw, t_g, t_b, t_m, t_v,
                                       p_dw, p_g, p_b, p_m, p_v,
                                       g_dw, g_g, g_b, g_m, g_v, hT, hP, hG);
  gemm_op_kernel<<<dim3(4, 49, 8), 256, 0, stream>>>(pwT, hT, th, t_pb);
  gemm_op_kernel<<<dim3(4, 49, 8), 256, 0, stream>>>(pwP, hP, ph, p_pb);
  gemm_g_kernel<<<dim3(49, 16, 8), 256, 0, stream>>>(hG, pwG, gg, bnscl, bnsft);
  adj_accum_kernel<<<512, 256, 0, stream>>>(th, ph, adj_raw);
  adj_softmax_kernel<<<4, 256, 0, stream>>>(adj_raw, adj);
  hf_kernel<<<dim3(196, 1, 8), 256, 0, stream>>>(gg, adj, hf);
  attn_kernel<<<1, 128, 0, stream>>>(hf, heads_w, attn);
  out_compute_kernel<<<dim3(196, 8), 256, 0, stream>>>(gg, adj, attn, ztmp);
  zres_kernel<<<dim3(49, 4, 8), 256, 0, stream>>>(ztmp, x, out);
}

// Round 4
// 456.985 us; speedup vs baseline: 1.4691x; 1.4691x over previous
//
#include <hip/hip_runtime.h>
#include <hip/hip_bf16.h>

typedef __hip_bfloat16 bf16;
typedef __attribute__((ext_vector_type(4))) float f32x4;
typedef __attribute__((ext_vector_type(8))) short s16x8;

#define DEV static __device__ __forceinline__

namespace {

constexpr float kEPS = 1e-5f;
constexpr float kFACTOR = 1.0f / 112.0f;  // 1/sqrt(196*64)

DEV float hswish_f(float v) { return v * fminf(fmaxf(v + 3.f, 0.f), 6.f) * (1.f / 6.f); }

// ---- K0: convert pointwise weights fp32 -> bf16 (+ reorder G to c*8+h rows,
//          precompute bn2 scale/shift in storage order) ---------------------
__global__ void cvt_pw_kernel(const float* __restrict__ a,
                              const float* __restrict__ b,
                              const float* __restrict__ cG,
                              const float* __restrict__ g2g, const float* __restrict__ g2b,
                              const float* __restrict__ g2m, const float* __restrict__ g2v,
                              bf16* __restrict__ oa, bf16* __restrict__ ob,
                              bf16* __restrict__ oc, float* __restrict__ bnscl,
                              float* __restrict__ bnsft) {
  int i = blockIdx.x * 256 + threadIdx.x;
  if (i < 512 * 256) {
    oa[i] = __float2bfloat16(a[i]);
    ob[i] = __float2bfloat16(b[i]);
  }
  if (i < 2048 * 256) {
    int r = i >> 8, k = i & 255;          // ref row r = h*256+c
    int h = r >> 8, c = r & 255;
    oc[(c * 8 + h) * 256 + k] = __float2bfloat16(cG[i]);
  }
  if (i < 2048) {                         // storage o = c*8+h
    int c = i >> 3, h = i & 7, ref = h * 256 + c;
    float s = g2g[ref] * rsqrtf(g2v[ref] + kEPS);
    bnscl[i] = s;
    bnsft[i] = g2b[ref] - g2m[ref] * s;
  }
}

// ---- K1: depthwise conv(1,3,3)+BN+hswish, 3 branches ---------------------
__global__ __launch_bounds__(256) void conv_kernel(
    const float* __restrict__ x,
    const float* __restrict__ tdw, const float* __restrict__ tg,
    const float* __restrict__ tb, const float* __restrict__ tm, const float* __restrict__ tv,
    const float* __restrict__ pdw, const float* __restrict__ pg,
    const float* __restrict__ pb, const float* __restrict__ pm, const float* __restrict__ pv,
    const float* __restrict__ gdw, const float* __restrict__ gG,
    const float* __restrict__ gb, const float* __restrict__ gm, const float* __restrict__ gv,
    bf16* __restrict__ h_t, bf16* __restrict__ h_p, bf16* __restrict__ h_g) {
  int bid = blockIdx.x;
  int cb = bid & 3, t = (bid >> 2) & 15, n = bid >> 6;
  int c0 = cb * 64;
  __shared__ float xs[64][197];
  __shared__ float wts[3][64][9];
  __shared__ float sc[3][64], sh[3][64];
  int tid = threadIdx.x;
  for (int i = tid; i < 64 * 9; i += 256) {
    int cl = i / 9, k = i % 9;
    wts[0][cl][k] = tdw[(c0 + cl) * 9 + k];
    wts[1][cl][k] = pdw[(c0 + cl) * 9 + k];
    wts[2][cl][k] = gdw[(c0 + cl) * 9 + k];
  }
  if (tid < 64) {
    int c = c0 + tid;
    float s0 = tg[c] * rsqrtf(tv[c] + kEPS);
    sc[0][tid] = s0; sh[0][tid] = tb[c] - tm[c] * s0;
    float s1 = pg[c] * rsqrtf(pv[c] + kEPS);
    sc[1][tid] = s1; sh[1][tid] = pb[c] - pm[c] * s1;
    float s2 = gG[c] * rsqrtf(gv[c] + kEPS);
    sc[2][tid] = s2; sh[2][tid] = gb[c] - gm[c] * s2;
  }
  const float* xb = x + ((size_t)(n * 256 + c0) * 16 + t) * 196;
  for (int i = tid; i < 64 * 196; i += 256) {
    int cl = i / 196, s = i % 196;
    xs[cl][s] = xb[(size_t)cl * 3136 + s];
  }
  __syncthreads();
  for (int i = tid; i < 64 * 196; i += 256) {
    int cl = i & 63, sp = i >> 6;
    int hs = sp / 14, wsp = sp % 14;
    float a0 = 0.f, a1 = 0.f, a2 = 0.f;
    #pragma unroll
    for (int dy = -1; dy <= 1; ++dy) {
      int yy = hs + dy;
      if (yy < 0 || yy >= 14) continue;
      #pragma unroll
      for (int dx = -1; dx <= 1; ++dx) {
        int xx = wsp + dx;
        if (xx < 0 || xx >= 14) continue;
        float v = xs[cl][yy * 14 + xx];
        int k = (dy + 1) * 3 + (dx + 1);
        a0 = fmaf(wts[0][cl][k], v, a0);
        a1 = fmaf(wts[1][cl][k], v, a1);
        a2 = fmaf(wts[2][cl][k], v, a2);
      }
    }
    a0 = hswish_f(a0 * sc[0][cl] + sh[0][cl]);
    a1 = hswish_f(a1 * sc[1][cl] + sh[1][cl]);
    a2 = hswish_f(a2 * sc[2][cl] + sh[2][cl]);
    size_t oidx = ((size_t)n * 3136 + t * 196 + sp) * 256 + c0 + cl;
    h_t[oidx] = __float2bfloat16(a0);
    h_p[oidx] = __float2bfloat16(a1);
    h_g[oidx] = __float2bfloat16(a2);
  }
}

// ---- K2a: bf16 MFMA GEMM  D[n][o][ts] = sum_c W[o][c]*H[ts][c] + bias ----
__global__ __launch_bounds__(256) void gemm_op_kernel(
    const bf16* __restrict__ A,  // W [512][256]
    const bf16* __restrict__ B,  // H [8][3136][256]
    bf16* __restrict__ D,        // [8][512][3136]
    const float* __restrict__ bias) {
  int mt = blockIdx.x, nt = blockIdx.y, n = blockIdx.z;
  __shared__ __align__(16) bf16 lds_a[128 * 64];
  __shared__ __align__(16) bf16 lds_b[64 * 64];
  int tid = threadIdx.x;
  int wid = tid >> 6, lane = tid & 63;
  int wr = wid >> 1, wc = wid & 1;
  int l15 = lane & 15, lh = lane >> 4;
  f32x4 acc[4][2];
  #pragma unroll
  for (int m = 0; m < 4; ++m)
    #pragma unroll
    for (int q = 0; q < 2; ++q) acc[m][q] = (f32x4){0.f, 0.f, 0.f, 0.f};
  const bf16* Ab = A + (size_t)mt * 128 * 256;
  const bf16* Bb = B + ((size_t)n * 3136 + (size_t)nt * 64) * 256;
  for (int k0 = 0; k0 < 256; k0 += 64) {
    #pragma unroll
    for (int it = 0; it < 4; ++it) {
      int g = tid + it * 256;
      int row = g >> 3, c16 = g & 7;
      int4 v = *(const int4*)(Ab + (size_t)row * 256 + k0 + c16 * 8);
      *(int4*)((char*)lds_a + row * 128 + ((c16 * 16) ^ ((row & 7) << 4))) = v;
    }
    #pragma unroll
    for (int it = 0; it < 2; ++it) {
      int g = tid + it * 256;
      int row = g >> 3, c16 = g & 7;
      int4 v = *(const int4*)(Bb + (size_t)row * 256 + k0 + c16 * 8);
      *(int4*)((char*)lds_b + row * 128 + ((c16 * 16) ^ ((row & 7) << 4))) = v;
    }
    __syncthreads();
    #pragma unroll
    for (int kk = 0; kk < 64; kk += 32) {
      s16x8 af[4], bfr[2];
      #pragma unroll
      for (int m = 0; m < 4; ++m) {
        int row = wr * 64 + m * 16 + l15;
        af[m] = *(const s16x8*)((const char*)lds_a + row * 128 +
                                (((kk + lh * 8) * 2) ^ ((row & 7) << 4)));
      }
      #pragma unroll
      for (int q = 0; q < 2; ++q) {
        int row = wc * 32 + q * 16 + l15;
        bfr[q] = *(const s16x8*)((const char*)lds_b + row * 128 +
                                 (((kk + lh * 8) * 2) ^ ((row & 7) << 4)));
      }
      #pragma unroll
      for (int m = 0; m < 4; ++m)
        #pragma unroll
        for (int q = 0; q < 2; ++q)
          acc[m][q] = __builtin_amdgcn_mfma_f32_16x16x32_bf16(af[m], bfr[q], acc[m][q], 0, 0, 0);
    }
    __syncthreads();
  }
  #pragma unroll
  for (int m = 0; m < 4; ++m) {
    #pragma unroll
    for (int q = 0; q < 2; ++q) {
      int col = nt * 64 + wc * 32 + q * 16 + l15;
      #pragma unroll
      for (int r = 0; r < 4; ++r) {
        int orow = mt * 128 + wr * 64 + m * 16 + lh * 4 + r;
        float v = acc[m][q][r] + bias[orow];
        D[((size_t)n * 512 + orow) * 3136 + col] = __float2bfloat16(v);
      }
    }
  }
}

// ---- K2b: transposed-output GEMM for g-branch ----------------------------
__global__ __launch_bounds__(256) void gemm_g_kernel(
    const bf16* __restrict__ A,   // hG [8][3136][256]
    const bf16* __restrict__ W,   // pwG [2048][256]
    bf16* __restrict__ D,         // gg [8][3136][2048]
    const float* __restrict__ bnscl, const float* __restrict__ bnsft) {
  int tsb = blockIdx.x, otb = blockIdx.y, n = blockIdx.z;
  __shared__ __align__(16) bf16 lds_a[64 * 64];
  __shared__ __align__(16) bf16 lds_b[128 * 64];
  int tid = threadIdx.x;
  int wid = tid >> 6, lane = tid & 63;
  int wr = wid >> 1, wc = wid & 1;
  int l15 = lane & 15, lh = lane >> 4;
  f32x4 acc[2][4];
  #pragma unroll
  for (int m = 0; m < 2; ++m)
    #pragma unroll
    for (int q = 0; q < 4; ++q) acc[m][q] = (f32x4){0.f, 0.f, 0.f, 0.f};
  const bf16* Ab = A + ((size_t)n * 3136 + (size_t)tsb * 64) * 256;
  const bf16* Wb = W + (size_t)otb * 128 * 256;
  for (int k0 = 0; k0 < 256; k0 += 64) {
    #pragma unroll
    for (int it = 0; it < 2; ++it) {
      int g = tid + it * 256;
      int row = g >> 3, c16 = g & 7;
      int4 v = *(const int4*)(Ab + (size_t)row * 256 + k0 + c16 * 8);
      *(int4*)((char*)lds_a + row * 128 + ((c16 * 16) ^ ((row & 7) << 4))) = v;
    }
    #pragma unroll
    for (int it = 0; it < 4; ++it) {
      int g = tid + it * 256;
      int row = g >> 3, c16 = g & 7;
      int4 v = *(const int4*)(Wb + (size_t)row * 256 + k0 + c16 * 8);
      *(int4*)((char*)lds_b + row * 128 + ((c16 * 16) ^ ((row & 7) << 4))) = v;
    }
    __syncthreads();
    #pragma unroll
    for (int kk = 0; kk < 64; kk += 32) {
      s16x8 af[2], bfr[4];
      #pragma unroll
      for (int m = 0; m < 2; ++m) {
        int row = wr * 32 + m * 16 + l15;
        af[m] = *(const s16x8*)((const char*)lds_a + row * 128 +
                                (((kk + lh * 8) * 2) ^ ((row & 7) << 4)));
      }
      #pragma unroll
      for (int q = 0; q < 4; ++q) {
        int row = wc * 64 + q * 16 + l15;
        bfr[q] = *(const s16x8*)((const char*)lds_b + row * 128 +
                                 (((kk + lh * 8) * 2) ^ ((row & 7) << 4)));
      }
      #pragma unroll
      for (int m = 0; m < 2; ++m)
        #pragma unroll
        for (int q = 0; q < 4; ++q)
          acc[m][q] = __builtin_amdgcn_mfma_f32_16x16x32_bf16(af[m], bfr[q], acc[m][q], 0, 0, 0);
    }
    __syncthreads();
  }
  #pragma unroll
  for (int q = 0; q < 4; ++q) {
    int ocol = otb * 128 + wc * 64 + q * 16 + l15;
    float scl = bnscl[ocol], sft = bnsft[ocol];
    #pragma unroll
    for (int m = 0; m < 2; ++m) {
      #pragma unroll
      for (int r = 0; r < 4; ++r) {
        int tsrow = tsb * 64 + wr * 32 + m * 16 + lh * 4 + r;
        float v = hswish_f(acc[m][q][r] * scl + sft);
        D[((size_t)n * 3136 + tsrow) * 2048 + ocol] = __float2bfloat16(v);
      }
    }
  }
}

// ---- K3: adjacency logits, partial over e-blocks (atomicAdd) -------------
__global__ __launch_bounds__(256) void adj_accum_kernel(const bf16* __restrict__ th,
                                                        const bf16* __restrict__ ph,
                                                        float* __restrict__ adj_raw) {
  int bid = blockIdx.x;
  int eb = bid & 7, h = (bid >> 3) & 7, n = bid >> 6;
  __shared__ __align__(16) float As[16 * 196];
  __shared__ __align__(16) float Bs[16 * 196];
  int tid = threadIdx.x;
  int t = tid >> 4, u = tid & 15;
  float acc = 0.f;
  for (int e8 = 0; e8 < 8; ++e8) {
    int e = eb * 8 + e8;
    const bf16* tp = th + ((size_t)n * 512 + h * 64 + e) * 3136;
    const bf16* pp = ph + ((size_t)n * 512 + h * 64 + e) * 3136;
    __syncthreads();
    for (int i = tid; i < 3136; i += 256) {
      As[i] = __bfloat162float(tp[i]);
      Bs[i] = __bfloat162float(pp[i]);
    }
    __syncthreads();
    const float* ar = As + t * 196;
    const float* br = Bs + u * 196;
    #pragma unroll
    for (int j = 0; j < 49; ++j) {
      f32x4 a = *(const f32x4*)(ar + j * 4);
      f32x4 b = *(const f32x4*)(br + j * 4);
      acc = fmaf(a[0], b[0], acc); acc = fmaf(a[1], b[1], acc);
      acc = fmaf(a[2], b[2], acc); acc = fmaf(a[3], b[3], acc);
    }
  }
  atomicAdd(&adj_raw[((n * 8 + h) * 16 + t) * 16 + u], acc);
}

// ---- K3b: softmax over u (16), with FACTOR -------------------------------
__global__ void adj_softmax_kernel(const float* __restrict__ raw, float* __restrict__ adj) {
  int r = blockIdx.x * 256 + threadIdx.x;
  if (r >= 1024) return;
  const float* p = raw + r * 16;
  float* q = adj + r * 16;
  float v[16], mx = -1e30f;
  #pragma unroll
  for (int u = 0; u < 16; ++u) { v[u] = p[u] * kFACTOR; mx = fmaxf(mx, v[u]); }
  float s = 0.f;
  #pragma unroll
  for (int u = 0; u < 16; ++u) { v[u] = __expf(v[u] - mx); s += v[u]; }
  float inv = 1.f / s;
  #pragma unroll
  for (int u = 0; u < 16; ++u) q[u] = v[u] * inv;
}

// ---- K4/K6 unified consumer: LDS-staged gg pass --------------------------
// block = (s, o-half, n). Stage ggL[16u][1024o'] (32KB) + adjL (8KB, padded).
// Thread owns o' = tid + k*256 -> h = tid&7 fixed, c' = (tid>>3)+k*32.
// EPI=0: hf[n][t][h] += sum_{c'} hswish(z)        (shuffle over c-lanes)
// EPI=1: ztmp[n][ts][c] = sum_h attn*hswish(z)    (shuffle over h-lanes)
template <int EPI>
__global__ __launch_bounds__(256) void consume_kernel(
    const bf16* __restrict__ gg, const float* __restrict__ adj,
    const float* __restrict__ attn, float* __restrict__ hf,
    bf16* __restrict__ ztmp) {
  int s = blockIdx.x, oh = blockIdx.y, n = blockIdx.z;
  __shared__ __align__(16) bf16 ggL[16][1024];   // 32 KB
  __shared__ __align__(16) float adjL[8][260];   // 8.3 KB, 260 pad: banks h*4
  __shared__ __align__(16) char aux[4096];       // zL (EPI=1) / hfp (EPI=0)
  bf16(*zL)[128] = (bf16(*)[128])aux;            // [16][128]
  float(*hfp)[8][16] = (float(*)[8][16])aux;     // [4][8][16]
  int tid = threadIdx.x;
  int h = tid & 7;
  for (int i = tid; i < 2048; i += 256) adjL[i >> 8][i & 255] = adj[n * 2048 + i];
  const bf16* gsrc = gg + ((size_t)n * 3136 + s) * 2048 + oh * 1024;
  #pragma unroll
  for (int u = 0; u < 16; ++u)
    *(int2*)&ggL[u][tid * 4] = *(const int2*)(gsrc + (size_t)u * 196 * 2048 + tid * 4);
  float atn[16];
  if (EPI == 1) {
    #pragma unroll
    for (int t = 0; t < 16; ++t) atn[t] = attn[n * 128 + t * 8 + h];
  }
  __syncthreads();
  float hacc[16];
  if (EPI == 0) {
    #pragma unroll
    for (int t = 0; t < 16; ++t) hacc[t] = 0.f;
  }
  #pragma unroll
  for (int tb = 0; tb < 4; ++tb) {
    f32x4 aj[4][4];
    #pragma unroll
    for (int tt = 0; tt < 4; ++tt)
      #pragma unroll
      for (int u4 = 0; u4 < 4; ++u4)
        aj[tt][u4] = *(const f32x4*)&adjL[h][(tb * 4 + tt) * 16 + u4 * 4];
    #pragma unroll
    for (int k = 0; k < 4; ++k) {
      int op = tid + k * 256;
      float gv[16];
      #pragma unroll
      for (int u = 0; u < 16; ++u) gv[u] = __bfloat162float(ggL[u][op]);
      float zp[4];
      #pragma unroll
      for (int tt = 0; tt < 4; ++tt) {
        float z = 0.f;
        #pragma unroll
        for (int u4 = 0; u4 < 4; ++u4) {
          z = fmaf(aj[tt][u4][0], gv[u4 * 4 + 0], z);
          z = fmaf(aj[tt][u4][1], gv[u4 * 4 + 1], z);
          z = fmaf(aj[tt][u4][2], gv[u4 * 4 + 2], z);
          z = fmaf(aj[tt][u4][3], gv[u4 * 4 + 3], z);
        }
        if (EPI == 0) hacc[tb * 4 + tt] += hswish_f(z);
        else zp[tt] = atn[tb * 4 + tt] * hswish_f(z);
      }
      if (EPI == 1) {
        #pragma unroll
        for (int tt = 0; tt < 4; ++tt) {
          zp[tt] += __shfl_xor(zp[tt], 1);
          zp[tt] += __shfl_xor(zp[tt], 2);
          zp[tt] += __shfl_xor(zp[tt], 4);
        }
        if (h < 4)  // lane h writes t = tb*4+h for its c'
          zL[tb * 4 + h][(tid >> 3) + k * 32] = __float2bfloat16(zp[h]);
      }
    }
  }
  if (EPI == 0) {
    #pragma unroll
    for (int t = 0; t < 16; ++t) {
      hacc[t] += __shfl_xor(hacc[t], 8);
      hacc[t] += __shfl_xor(hacc[t], 16);
      hacc[t] += __shfl_xor(hacc[t], 32);
    }
    if ((tid & 63) < 8) {
      #pragma unroll
      for (int t = 0; t < 16; ++t) hfp[tid >> 6][h][t] = hacc[t];
    }
    __syncthreads();
    if (tid < 128) {
      int h2 = tid & 7, t2 = tid >> 3;
      float v = hfp[0][h2][t2] + hfp[1][h2][t2] + hfp[2][h2][t2] + hfp[3][h2][t2];
      atomicAdd(&hf[n * 128 + t2 * 8 + h2], v);
    }
  } else {
    __syncthreads();
    int t = tid >> 4, cq = tid & 15;
    int4 v = *(const int4*)&zL[t][cq * 8];
    *(int4*)(ztmp + ((size_t)n * 3136 + t * 196 + s) * 256 + oh * 128 + cq * 8) = v;
  }
}

// ---- K5: head-mix attn = softmax(hf_mean @ heads_w) ----------------------
__global__ void attn_kernel(const float* __restrict__ hf, const float* __restrict__ hw,
                            float* __restrict__ attn) {
  int tid = threadIdx.x;
  if (tid >= 128) return;
  int n = tid >> 4, t = tid & 15;
  const float inv = 1.0f / (256.0f * 196.0f);
  float hm[8];
  #pragma unroll
  for (int h = 0; h < 8; ++h) hm[h] = hf[(n * 16 + t) * 8 + h] * inv;
  float o[8], mx = -1e30f;
  #pragma unroll
  for (int h2 = 0; h2 < 8; ++h2) {
    float s = 0.f;
    #pragma unroll
    for (int h = 0; h < 8; ++h) s = fmaf(hm[h], hw[h * 8 + h2], s);
    o[h2] = s; mx = fmaxf(mx, s);
  }
  float s = 0.f;
  #pragma unroll
  for (int h2 = 0; h2 < 8; ++h2) { o[h2] = __expf(o[h2] - mx); s += o[h2]; }
  float is = 1.f / s;
  #pragma unroll
  for (int h2 = 0; h2 < 8; ++h2) attn[(n * 16 + t) * 8 + h2] = o[h2] * is;
}

// ---- K7: transpose z [ts][c]->[c][ts], add residual, final hswish --------
__global__ __launch_bounds__(256) void zres_kernel(const bf16* __restrict__ ztmp,
                                                   const float* __restrict__ x,
                                                   float* __restrict__ out) {
  int tsb = blockIdx.x, cb = blockIdx.y, n = blockIdx.z;
  __shared__ __align__(16) bf16 tile[64 * 64];
  int tid = threadIdx.x;
  #pragma unroll
  for (int it = 0; it < 2; ++it) {
    int g = tid + it * 256;
    int row = g >> 3, cq = g & 7;
    int4 v = *(const int4*)(ztmp + ((size_t)n * 3136 + tsb * 64 + row) * 256 + cb * 64 + cq * 8);
    *(int4*)((char*)tile + row * 128 + ((cq * 16) ^ ((row & 7) << 4))) = v;
  }
  __syncthreads();
  int cl = tid & 63, tq = tid >> 6;
  size_t obase = ((size_t)(n * 256 + cb * 64 + cl)) * 3136 + tsb * 64 + tq * 16;
  #pragma unroll
  for (int i = 0; i < 16; i += 4) {
    f32x4 xv = *(const f32x4*)(x + obase + i);
    f32x4 r;
    #pragma unroll
    for (int j = 0; j < 4; ++j) {
      int row = tq * 16 + i + j;
      unsigned short zb = *(const unsigned short*)((const char*)tile + row * 128 +
                                                   ((cl * 2) ^ ((row & 7) << 4)));
      float z = __uint_as_float((unsigned)zb << 16);
      r[j] = hswish_f(xv[j] + z);
    }
    *(f32x4*)(out + obase + i) = r;
  }
}

}  // namespace

extern "C" void kernel_launch(void* const* d_in, const int* in_sizes, int n_in,
                              void* d_out, int out_size, void* d_ws, size_t ws_size,
                              hipStream_t stream) {
  const float* x       = (const float*)d_in[0];
  const float* t_dw    = (const float*)d_in[1];
  const float* t_g     = (const float*)d_in[2];
  const float* t_b     = (const float*)d_in[3];
  const float* t_m     = (const float*)d_in[4];
  const float* t_v     = (const float*)d_in[5];
  const float* t_pw    = (const float*)d_in[6];
  const float* p_dw    = (const float*)d_in[7];
  const float* p_g     = (const float*)d_in[8];
  const float* p_b     = (const float*)d_in[9];
  const float* p_m     = (const float*)d_in[10];
  const float* p_v     = (const float*)d_in[11];
  const float* p_pw    = (const float*)d_in[12];
  const float* g_dw    = (const float*)d_in[13];
  const float* g_g     = (const float*)d_in[14];
  const float* g_b     = (const float*)d_in[15];
  const float* g_m     = (const float*)d_in[16];
  const float* g_v     = (const float*)d_in[17];
  const float* g_pw    = (const float*)d_in[18];
  const float* t_pb    = (const float*)d_in[19];
  const float* p_pb    = (const float*)d_in[20];
  const float* g2_g    = (const float*)d_in[21];
  const float* g2_b    = (const float*)d_in[22];
  const float* g2_m    = (const float*)d_in[23];
  const float* g2_v    = (const float*)d_in[24];
  const float* heads_w = (const float*)d_in[25];
  float* out = (float*)d_out;
  (void)in_sizes; (void)n_in; (void)out_size; (void)ws_size;

  char* w = (char*)d_ws;
  size_t off = 0;
  auto take = [&](size_t bytes) {
    char* p = w + off;
    off = (off + bytes + 255) & ~(size_t)255;
    return p;
  };
  bf16* pwT = (bf16*)take(512 * 256 * 2);
  bf16* pwP = (bf16*)take(512 * 256 * 2);
  bf16* pwG = (bf16*)take(2048 * 256 * 2);
  float* bnscl = (float*)take(2048 * 4);
  float* bnsft = (float*)take(2048 * 4);
  bf16* hT  = (bf16*)take((size_t)8 * 3136 * 256 * 2);
  bf16* hP  = (bf16*)take((size_t)8 * 3136 * 256 * 2);
  bf16* hG  = (bf16*)take((size_t)8 * 3136 * 256 * 2);
  bf16* th  = (bf16*)take((size_t)8 * 512 * 3136 * 2);
  bf16* ph  = (bf16*)take((size_t)8 * 512 * 3136 * 2);
  bf16* gg  = (bf16*)take((size_t)8 * 3136 * 2048 * 2);
  float* adj_raw = (float*)take(1024 * 16 * 4);
  float* adj     = (float*)take(1024 * 16 * 4);
  float* hf      = (float*)take(1024 * 4);
  float* attn    = (float*)take(1024 * 4);
  bf16* ztmp = hT;  // hT dead after gemm_op theta

  hipMemsetAsync(adj_raw, 0, 1024 * 16 * 4, stream);
  hipMemsetAsync(hf, 0, 1024 * 4, stream);

  cvt_pw_kernel<<<2048, 256, 0, stream>>>(t_pw, p_pw, g_pw, g2_g, g2_b, g2_m, g2_v,
                                          pwT, pwP, pwG, bnscl, bnsft);
  conv_kernel<<<512, 256, 0, stream>>>(x, t_dw, t_g, t_b, t_m, t_v,
                                       p_dw, p_g, p_b, p_m, p_v,
                                       g_dw, g_g, g_b, g_m, g_v, hT, hP, hG);
  gemm_op_kernel<<<dim3(4, 49, 8), 256, 0, stream>>>(pwT, hT, th, t_pb);
  gemm_op_kernel<<<dim3(4, 49, 8), 256, 0, stream>>>(pwP, hP, ph, p_pb);
  gemm_g_kernel<<<dim3(49, 16, 8), 256, 0, stream>>>(hG, pwG, gg, bnscl, bnsft);
  adj_accum_kernel<<<512, 256, 0, stream>>>(th, ph, adj_raw);
  adj_softmax_kernel<<<4, 256, 0, stream>>>(adj_raw, adj);
  consume_kernel<0><<<dim3(196, 2, 8), 256, 0, stream>>>(gg, adj, nullptr, hf, nullptr);
  attn_kernel<<<1, 128, 0, stream>>>(hf, heads_w, attn);
  consume_kernel<1><<<dim3(196, 2, 8), 256, 0, stream>>>(gg, adj, attn, nullptr, ztmp);
  zres_kernel<<<dim3(49, 4, 8), 256, 0, stream>>>(ztmp, x, out);
}

// Round 5
// 452.487 us; speedup vs baseline: 1.4837x; 1.0099x over previous
//
#include <hip/hip_runtime.h>
#include <hip/hip_bf16.h>

typedef __hip_bfloat16 bf16;
typedef __attribute__((ext_vector_type(4))) float f32x4;
typedef __attribute__((ext_vector_type(8))) short s16x8;

#define DEV static __device__ __forceinline__

namespace {

constexpr float kEPS = 1e-5f;
constexpr float kFACTOR = 1.0f / 112.0f;  // 1/sqrt(196*64)

DEV float hswish_f(float v) { return v * fminf(fmaxf(v + 3.f, 0.f), 6.f) * (1.f / 6.f); }

// ---- K0: convert pointwise weights fp32 -> bf16 (+ reorder G to c*8+h rows,
//          precompute bn2 scale/shift in storage order) ---------------------
__global__ void cvt_pw_kernel(const float* __restrict__ a,
                              const float* __restrict__ b,
                              const float* __restrict__ cG,
                              const float* __restrict__ g2g, const float* __restrict__ g2b,
                              const float* __restrict__ g2m, const float* __restrict__ g2v,
                              bf16* __restrict__ oa, bf16* __restrict__ ob,
                              bf16* __restrict__ oc, float* __restrict__ bnscl,
                              float* __restrict__ bnsft) {
  int i = blockIdx.x * 256 + threadIdx.x;
  if (i < 512 * 256) {
    oa[i] = __float2bfloat16(a[i]);
    ob[i] = __float2bfloat16(b[i]);
  }
  if (i < 2048 * 256) {
    int r = i >> 8, k = i & 255;          // ref row r = h*256+c
    int h = r >> 8, c = r & 255;
    oc[(c * 8 + h) * 256 + k] = __float2bfloat16(cG[i]);
  }
  if (i < 2048) {                         // storage o = c*8+h
    int c = i >> 3, h = i & 7, ref = h * 256 + c;
    float s = g2g[ref] * rsqrtf(g2v[ref] + kEPS);
    bnscl[i] = s;
    bnsft[i] = g2b[ref] - g2m[ref] * s;
  }
}

// ---- K1: depthwise conv(1,3,3)+BN+hswish, 3 branches ---------------------
__global__ __launch_bounds__(256) void conv_kernel(
    const float* __restrict__ x,
    const float* __restrict__ tdw, const float* __restrict__ tg,
    const float* __restrict__ tb, const float* __restrict__ tm, const float* __restrict__ tv,
    const float* __restrict__ pdw, const float* __restrict__ pg,
    const float* __restrict__ pb, const float* __restrict__ pm, const float* __restrict__ pv,
    const float* __restrict__ gdw, const float* __restrict__ gG,
    const float* __restrict__ gb, const float* __restrict__ gm, const float* __restrict__ gv,
    bf16* __restrict__ h_t, bf16* __restrict__ h_p, bf16* __restrict__ h_g) {
  int bid = blockIdx.x;
  int cb = bid & 3, t = (bid >> 2) & 15, n = bid >> 6;
  int c0 = cb * 64;
  __shared__ float xs[64][197];
  __shared__ float wts[3][64][9];
  __shared__ float sc[3][64], sh[3][64];
  int tid = threadIdx.x;
  for (int i = tid; i < 64 * 9; i += 256) {
    int cl = i / 9, k = i % 9;
    wts[0][cl][k] = tdw[(c0 + cl) * 9 + k];
    wts[1][cl][k] = pdw[(c0 + cl) * 9 + k];
    wts[2][cl][k] = gdw[(c0 + cl) * 9 + k];
  }
  if (tid < 64) {
    int c = c0 + tid;
    float s0 = tg[c] * rsqrtf(tv[c] + kEPS);
    sc[0][tid] = s0; sh[0][tid] = tb[c] - tm[c] * s0;
    float s1 = pg[c] * rsqrtf(pv[c] + kEPS);
    sc[1][tid] = s1; sh[1][tid] = pb[c] - pm[c] * s1;
    float s2 = gG[c] * rsqrtf(gv[c] + kEPS);
    sc[2][tid] = s2; sh[2][tid] = gb[c] - gm[c] * s2;
  }
  const float* xb = x + ((size_t)(n * 256 + c0) * 16 + t) * 196;
  for (int i = tid; i < 64 * 196; i += 256) {
    int cl = i / 196, s = i % 196;
    xs[cl][s] = xb[(size_t)cl * 3136 + s];
  }
  __syncthreads();
  for (int i = tid; i < 64 * 196; i += 256) {
    int cl = i & 63, sp = i >> 6;
    int hs = sp / 14, wsp = sp % 14;
    float a0 = 0.f, a1 = 0.f, a2 = 0.f;
    #pragma unroll
    for (int dy = -1; dy <= 1; ++dy) {
      int yy = hs + dy;
      if (yy < 0 || yy >= 14) continue;
      #pragma unroll
      for (int dx = -1; dx <= 1; ++dx) {
        int xx = wsp + dx;
        if (xx < 0 || xx >= 14) continue;
        float v = xs[cl][yy * 14 + xx];
        int k = (dy + 1) * 3 + (dx + 1);
        a0 = fmaf(wts[0][cl][k], v, a0);
        a1 = fmaf(wts[1][cl][k], v, a1);
        a2 = fmaf(wts[2][cl][k], v, a2);
      }
    }
    a0 = hswish_f(a0 * sc[0][cl] + sh[0][cl]);
    a1 = hswish_f(a1 * sc[1][cl] + sh[1][cl]);
    a2 = hswish_f(a2 * sc[2][cl] + sh[2][cl]);
    size_t oidx = ((size_t)n * 3136 + t * 196 + sp) * 256 + c0 + cl;
    h_t[oidx] = __float2bfloat16(a0);
    h_p[oidx] = __float2bfloat16(a1);
    h_g[oidx] = __float2bfloat16(a2);
  }
}

// ---- K2a: bf16 MFMA GEMM  D[n][o][ts] = sum_c W[o][c]*H[ts][c] + bias ----
// Epilogue: stage C tile in LDS, write full 128B lines.
__global__ __launch_bounds__(256) void gemm_op_kernel(
    const bf16* __restrict__ A,  // W [512][256]
    const bf16* __restrict__ B,  // H [8][3136][256]
    bf16* __restrict__ D,        // [8][512][3136]
    const float* __restrict__ bias) {
  int mt = blockIdx.x, nt = blockIdx.y, n = blockIdx.z;
  __shared__ __align__(16) bf16 lds_a[128 * 64];   // 16 KB; reused as C tile
  __shared__ __align__(16) bf16 lds_b[64 * 64];
  int tid = threadIdx.x;
  int wid = tid >> 6, lane = tid & 63;
  int wr = wid >> 1, wc = wid & 1;
  int l15 = lane & 15, lh = lane >> 4;
  f32x4 acc[4][2];
  #pragma unroll
  for (int m = 0; m < 4; ++m)
    #pragma unroll
    for (int q = 0; q < 2; ++q) acc[m][q] = (f32x4){0.f, 0.f, 0.f, 0.f};
  const bf16* Ab = A + (size_t)mt * 128 * 256;
  const bf16* Bb = B + ((size_t)n * 3136 + (size_t)nt * 64) * 256;
  for (int k0 = 0; k0 < 256; k0 += 64) {
    #pragma unroll
    for (int it = 0; it < 4; ++it) {
      int g = tid + it * 256;
      int row = g >> 3, c16 = g & 7;
      int4 v = *(const int4*)(Ab + (size_t)row * 256 + k0 + c16 * 8);
      *(int4*)((char*)lds_a + row * 128 + ((c16 * 16) ^ ((row & 7) << 4))) = v;
    }
    #pragma unroll
    for (int it = 0; it < 2; ++it) {
      int g = tid + it * 256;
      int row = g >> 3, c16 = g & 7;
      int4 v = *(const int4*)(Bb + (size_t)row * 256 + k0 + c16 * 8);
      *(int4*)((char*)lds_b + row * 128 + ((c16 * 16) ^ ((row & 7) << 4))) = v;
    }
    __syncthreads();
    #pragma unroll
    for (int kk = 0; kk < 64; kk += 32) {
      s16x8 af[4], bfr[2];
      #pragma unroll
      for (int m = 0; m < 4; ++m) {
        int row = wr * 64 + m * 16 + l15;
        af[m] = *(const s16x8*)((const char*)lds_a + row * 128 +
                                (((kk + lh * 8) * 2) ^ ((row & 7) << 4)));
      }
      #pragma unroll
      for (int q = 0; q < 2; ++q) {
        int row = wc * 32 + q * 16 + l15;
        bfr[q] = *(const s16x8*)((const char*)lds_b + row * 128 +
                                 (((kk + lh * 8) * 2) ^ ((row & 7) << 4)));
      }
      #pragma unroll
      for (int m = 0; m < 4; ++m)
        #pragma unroll
        for (int q = 0; q < 2; ++q)
          acc[m][q] = __builtin_amdgcn_mfma_f32_16x16x32_bf16(af[m], bfr[q], acc[m][q], 0, 0, 0);
    }
    __syncthreads();
  }
  // ---- epilogue: acc -> LDS [128 orow][64 col] swizzled, then full lines --
  #pragma unroll
  for (int m = 0; m < 4; ++m) {
    #pragma unroll
    for (int q = 0; q < 2; ++q) {
      int col = wc * 32 + q * 16 + l15;
      #pragma unroll
      for (int r = 0; r < 4; ++r) {
        int row = wr * 64 + m * 16 + lh * 4 + r;
        float v = acc[m][q][r] + bias[mt * 128 + row];
        *(bf16*)((char*)lds_a + row * 128 + ((col * 2) ^ ((row & 7) << 4))) =
            __float2bfloat16(v);
      }
    }
  }
  __syncthreads();
  #pragma unroll
  for (int it = 0; it < 4; ++it) {
    int g = tid + it * 256;            // 1024 granules of 16B: 128 rows x 8
    int row = g >> 3, cq = g & 7;
    int4 v = *(const int4*)((const char*)lds_a + row * 128 + ((cq * 16) ^ ((row & 7) << 4)));
    *(int4*)(D + ((size_t)n * 512 + mt * 128 + row) * 3136 + nt * 64 + cq * 8) = v;
  }
}

// ---- K2b: transposed-output GEMM for g-branch ----------------------------
// Epilogue: LDS-staged, full 256B-line writes.
__global__ __launch_bounds__(256) void gemm_g_kernel(
    const bf16* __restrict__ A,   // hG [8][3136][256]
    const bf16* __restrict__ W,   // pwG [2048][256]
    bf16* __restrict__ D,         // gg [8][3136][2048]
    const float* __restrict__ bnscl, const float* __restrict__ bnsft) {
  int tsb = blockIdx.x, otb = blockIdx.y, n = blockIdx.z;
  __shared__ __align__(16) bf16 lds_a[64 * 64];
  __shared__ __align__(16) bf16 lds_b[128 * 64];  // 16 KB; reused as C tile
  int tid = threadIdx.x;
  int wid = tid >> 6, lane = tid & 63;
  int wr = wid >> 1, wc = wid & 1;
  int l15 = lane & 15, lh = lane >> 4;
  f32x4 acc[2][4];
  #pragma unroll
  for (int m = 0; m < 2; ++m)
    #pragma unroll
    for (int q = 0; q < 4; ++q) acc[m][q] = (f32x4){0.f, 0.f, 0.f, 0.f};
  const bf16* Ab = A + ((size_t)n * 3136 + (size_t)tsb * 64) * 256;
  const bf16* Wb = W + (size_t)otb * 128 * 256;
  for (int k0 = 0; k0 < 256; k0 += 64) {
    #pragma unroll
    for (int it = 0; it < 2; ++it) {
      int g = tid + it * 256;
      int row = g >> 3, c16 = g & 7;
      int4 v = *(const int4*)(Ab + (size_t)row * 256 + k0 + c16 * 8);
      *(int4*)((char*)lds_a + row * 128 + ((c16 * 16) ^ ((row & 7) << 4))) = v;
    }
    #pragma unroll
    for (int it = 0; it < 4; ++it) {
      int g = tid + it * 256;
      int row = g >> 3, c16 = g & 7;
      int4 v = *(const int4*)(Wb + (size_t)row * 256 + k0 + c16 * 8);
      *(int4*)((char*)lds_b + row * 128 + ((c16 * 16) ^ ((row & 7) << 4))) = v;
    }
    __syncthreads();
    #pragma unroll
    for (int kk = 0; kk < 64; kk += 32) {
      s16x8 af[2], bfr[4];
      #pragma unroll
      for (int m = 0; m < 2; ++m) {
        int row = wr * 32 + m * 16 + l15;
        af[m] = *(const s16x8*)((const char*)lds_a + row * 128 +
                                (((kk + lh * 8) * 2) ^ ((row & 7) << 4)));
      }
      #pragma unroll
      for (int q = 0; q < 4; ++q) {
        int row = wc * 64 + q * 16 + l15;
        bfr[q] = *(const s16x8*)((const char*)lds_b + row * 128 +
                                 (((kk + lh * 8) * 2) ^ ((row & 7) << 4)));
      }
      #pragma unroll
      for (int m = 0; m < 2; ++m)
        #pragma unroll
        for (int q = 0; q < 4; ++q)
          acc[m][q] = __builtin_amdgcn_mfma_f32_16x16x32_bf16(af[m], bfr[q], acc[m][q], 0, 0, 0);
    }
    __syncthreads();
  }
  // ---- epilogue: acc -> LDS [64 tsrow][128 ocol] swizzled ------------------
  #pragma unroll
  for (int q = 0; q < 4; ++q) {
    int ocol = wc * 64 + q * 16 + l15;
    float scl = bnscl[otb * 128 + ocol], sft = bnsft[otb * 128 + ocol];
    #pragma unroll
    for (int m = 0; m < 2; ++m) {
      #pragma unroll
      for (int r = 0; r < 4; ++r) {
        int row = wr * 32 + m * 16 + lh * 4 + r;
        float v = hswish_f(acc[m][q][r] * scl + sft);
        *(bf16*)((char*)lds_b + row * 256 + ((ocol * 2) ^ ((row & 7) << 4))) =
            __float2bfloat16(v);
      }
    }
  }
  __syncthreads();
  #pragma unroll
  for (int it = 0; it < 4; ++it) {
    int g = tid + it * 256;            // 1024 granules of 16B: 64 rows x 16
    int row = g >> 4, cq = g & 15;
    int4 v = *(const int4*)((const char*)lds_b + row * 256 + ((cq * 16) ^ ((row & 7) << 4)));
    *(int4*)(D + ((size_t)n * 3136 + tsb * 64 + row) * 2048 + otb * 128 + cq * 8) = v;
  }
}

// ---- K3: adjacency logits, partial over e-blocks (atomicAdd) -------------
__global__ __launch_bounds__(256) void adj_accum_kernel(const bf16* __restrict__ th,
                                                        const bf16* __restrict__ ph,
                                                        float* __restrict__ adj_raw) {
  int bid = blockIdx.x;
  int eb = bid & 7, h = (bid >> 3) & 7, n = bid >> 6;
  __shared__ __align__(16) float As[16 * 196];
  __shared__ __align__(16) float Bs[16 * 196];
  int tid = threadIdx.x;
  int t = tid >> 4, u = tid & 15;
  float acc = 0.f;
  for (int e8 = 0; e8 < 8; ++e8) {
    int e = eb * 8 + e8;
    const bf16* tp = th + ((size_t)n * 512 + h * 64 + e) * 3136;
    const bf16* pp = ph + ((size_t)n * 512 + h * 64 + e) * 3136;
    __syncthreads();
    for (int i = tid; i < 3136; i += 256) {
      As[i] = __bfloat162float(tp[i]);
      Bs[i] = __bfloat162float(pp[i]);
    }
    __syncthreads();
    const float* ar = As + t * 196;
    const float* br = Bs + u * 196;
    #pragma unroll
    for (int j = 0; j < 49; ++j) {
      f32x4 a = *(const f32x4*)(ar + j * 4);
      f32x4 b = *(const f32x4*)(br + j * 4);
      acc = fmaf(a[0], b[0], acc); acc = fmaf(a[1], b[1], acc);
      acc = fmaf(a[2], b[2], acc); acc = fmaf(a[3], b[3], acc);
    }
  }
  atomicAdd(&adj_raw[((n * 8 + h) * 16 + t) * 16 + u], acc);
}

// ---- K3b: softmax over u (16), with FACTOR -------------------------------
__global__ void adj_softmax_kernel(const float* __restrict__ raw, float* __restrict__ adj) {
  int r = blockIdx.x * 256 + threadIdx.x;
  if (r >= 1024) return;
  const float* p = raw + r * 16;
  float* q = adj + r * 16;
  float v[16], mx = -1e30f;
  #pragma unroll
  for (int u = 0; u < 16; ++u) { v[u] = p[u] * kFACTOR; mx = fmaxf(mx, v[u]); }
  float s = 0.f;
  #pragma unroll
  for (int u = 0; u < 16; ++u) { v[u] = __expf(v[u] - mx); s += v[u]; }
  float inv = 1.f / s;
  #pragma unroll
  for (int u = 0; u < 16; ++u) q[u] = v[u] * inv;
}

// ---- K4/K6 unified consumer: LDS-staged gg pass --------------------------
template <int EPI>
__global__ __launch_bounds__(256) void consume_kernel(
    const bf16* __restrict__ gg, const float* __restrict__ adj,
    const float* __restrict__ attn, float* __restrict__ hf,
    bf16* __restrict__ ztmp) {
  int s = blockIdx.x, oh = blockIdx.y, n = blockIdx.z;
  __shared__ __align__(16) bf16 ggL[16][1024];   // 32 KB
  __shared__ __align__(16) float adjL[8][260];   // 8.3 KB
  __shared__ __align__(16) char aux[4096];       // zL (EPI=1) / hfp (EPI=0)
  bf16(*zL)[128] = (bf16(*)[128])aux;            // [16][128]
  float(*hfp)[8][16] = (float(*)[8][16])aux;     // [4][8][16]
  int tid = threadIdx.x;
  int h = tid & 7;
  for (int i = tid; i < 2048; i += 256) adjL[i >> 8][i & 255] = adj[n * 2048 + i];
  const bf16* gsrc = gg + ((size_t)n * 3136 + s) * 2048 + oh * 1024;
  #pragma unroll
  for (int u = 0; u < 16; ++u)
    *(int2*)&ggL[u][tid * 4] = *(const int2*)(gsrc + (size_t)u * 196 * 2048 + tid * 4);
  float atn[16];
  if (EPI == 1) {
    #pragma unroll
    for (int t = 0; t < 16; ++t) atn[t] = attn[n * 128 + t * 8 + h];
  }
  __syncthreads();
  float hacc[16];
  if (EPI == 0) {
    #pragma unroll
    for (int t = 0; t < 16; ++t) hacc[t] = 0.f;
  }
  #pragma unroll
  for (int tb = 0; tb < 4; ++tb) {
    f32x4 aj[4][4];
    #pragma unroll
    for (int tt = 0; tt < 4; ++tt)
      #pragma unroll
      for (int u4 = 0; u4 < 4; ++u4)
        aj[tt][u4] = *(const f32x4*)&adjL[h][(tb * 4 + tt) * 16 + u4 * 4];
    #pragma unroll
    for (int k = 0; k < 4; ++k) {
      int op = tid + k * 256;
      float gv[16];
      #pragma unroll
      for (int u = 0; u < 16; ++u) gv[u] = __bfloat162float(ggL[u][op]);
      float zp[4];
      #pragma unroll
      for (int tt = 0; tt < 4; ++tt) {
        float z = 0.f;
        #pragma unroll
        for (int u4 = 0; u4 < 4; ++u4) {
          z = fmaf(aj[tt][u4][0], gv[u4 * 4 + 0], z);
          z = fmaf(aj[tt][u4][1], gv[u4 * 4 + 1], z);
          z = fmaf(aj[tt][u4][2], gv[u4 * 4 + 2], z);
          z = fmaf(aj[tt][u4][3], gv[u4 * 4 + 3], z);
        }
        if (EPI == 0) hacc[tb * 4 + tt] += hswish_f(z);
        else zp[tt] = atn[tb * 4 + tt] * hswish_f(z);
      }
      if (EPI == 1) {
        #pragma unroll
        for (int tt = 0; tt < 4; ++tt) {
          zp[tt] += __shfl_xor(zp[tt], 1);
          zp[tt] += __shfl_xor(zp[tt], 2);
          zp[tt] += __shfl_xor(zp[tt], 4);
        }
        if (h < 4)
          zL[tb * 4 + h][(tid >> 3) + k * 32] = __float2bfloat16(zp[h]);
      }
    }
  }
  if (EPI == 0) {
    #pragma unroll
    for (int t = 0; t < 16; ++t) {
      hacc[t] += __shfl_xor(hacc[t], 8);
      hacc[t] += __shfl_xor(hacc[t], 16);
      hacc[t] += __shfl_xor(hacc[t], 32);
    }
    if ((tid & 63) < 8) {
      #pragma unroll
      for (int t = 0; t < 16; ++t) hfp[tid >> 6][h][t] = hacc[t];
    }
    __syncthreads();
    if (tid < 128) {
      int h2 = tid & 7, t2 = tid >> 3;
      float v = hfp[0][h2][t2] + hfp[1][h2][t2] + hfp[2][h2][t2] + hfp[3][h2][t2];
      atomicAdd(&hf[n * 128 + t2 * 8 + h2], v);
    }
  } else {
    __syncthreads();
    int t = tid >> 4, cq = tid & 15;
    int4 v = *(const int4*)&zL[t][cq * 8];
    *(int4*)(ztmp + ((size_t)n * 3136 + t * 196 + s) * 256 + oh * 128 + cq * 8) = v;
  }
}

// ---- K5: head-mix attn = softmax(hf_mean @ heads_w) ----------------------
__global__ void attn_kernel(const float* __restrict__ hf, const float* __restrict__ hw,
                            float* __restrict__ attn) {
  int tid = threadIdx.x;
  if (tid >= 128) return;
  int n = tid >> 4, t = tid & 15;
  const float inv = 1.0f / (256.0f * 196.0f);
  float hm[8];
  #pragma unroll
  for (int h = 0; h < 8; ++h) hm[h] = hf[(n * 16 + t) * 8 + h] * inv;
  float o[8], mx = -1e30f;
  #pragma unroll
  for (int h2 = 0; h2 < 8; ++h2) {
    float s = 0.f;
    #pragma unroll
    for (int h = 0; h < 8; ++h) s = fmaf(hm[h], hw[h * 8 + h2], s);
    o[h2] = s; mx = fmaxf(mx, s);
  }
  float s = 0.f;
  #pragma unroll
  for (int h2 = 0; h2 < 8; ++h2) { o[h2] = __expf(o[h2] - mx); s += o[h2]; }
  float is = 1.f / s;
  #pragma unroll
  for (int h2 = 0; h2 < 8; ++h2) attn[(n * 16 + t) * 8 + h2] = o[h2] * is;
}

// ---- K7: transpose z [ts][c]->[c][ts], add residual, final hswish --------
__global__ __launch_bounds__(256) void zres_kernel(const bf16* __restrict__ ztmp,
                                                   const float* __restrict__ x,
                                                   float* __restrict__ out) {
  int tsb = blockIdx.x, cb = blockIdx.y, n = blockIdx.z;
  __shared__ __align__(16) bf16 tile[64 * 64];
  int tid = threadIdx.x;
  #pragma unroll
  for (int it = 0; it < 2; ++it) {
    int g = tid + it * 256;
    int row = g >> 3, cq = g & 7;
    int4 v = *(const int4*)(ztmp + ((size_t)n * 3136 + tsb * 64 + row) * 256 + cb * 64 + cq * 8);
    *(int4*)((char*)tile + row * 128 + ((cq * 16) ^ ((row & 7) << 4))) = v;
  }
  __syncthreads();
  int cl = tid & 63, tq = tid >> 6;
  size_t obase = ((size_t)(n * 256 + cb * 64 + cl)) * 3136 + tsb * 64 + tq * 16;
  #pragma unroll
  for (int i = 0; i < 16; i += 4) {
    f32x4 xv = *(const f32x4*)(x + obase + i);
    f32x4 r;
    #pragma unroll
    for (int j = 0; j < 4; ++j) {
      int row = tq * 16 + i + j;
      unsigned short zb = *(const unsigned short*)((const char*)tile + row * 128 +
                                                   ((cl * 2) ^ ((row & 7) << 4)));
      float z = __uint_as_float((unsigned)zb << 16);
      r[j] = hswish_f(xv[j] + z);
    }
    *(f32x4*)(out + obase + i) = r;
  }
}

}  // namespace

extern "C" void kernel_launch(void* const* d_in, const int* in_sizes, int n_in,
                              void* d_out, int out_size, void* d_ws, size_t ws_size,
                              hipStream_t stream) {
  const float* x       = (const float*)d_in[0];
  const float* t_dw    = (const float*)d_in[1];
  const float* t_g     = (const float*)d_in[2];
  const float* t_b     = (const float*)d_in[3];
  const float* t_m     = (const float*)d_in[4];
  const float* t_v     = (const float*)d_in[5];
  const float* t_pw    = (const float*)d_in[6];
  const float* p_dw    = (const float*)d_in[7];
  const float* p_g     = (const float*)d_in[8];
  const float* p_b     = (const float*)d_in[9];
  const float* p_m     = (const float*)d_in[10];
  const float* p_v     = (const float*)d_in[11];
  const float* p_pw    = (const float*)d_in[12];
  const float* g_dw    = (const float*)d_in[13];
  const float* g_g     = (const float*)d_in[14];
  const float* g_b     = (const float*)d_in[15];
  const float* g_m     = (const float*)d_in[16];
  const float* g_v     = (const float*)d_in[17];
  const float* g_pw    = (const float*)d_in[18];
  const float* t_pb    = (const float*)d_in[19];
  const float* p_pb    = (const float*)d_in[20];
  const float* g2_g    = (const float*)d_in[21];
  const float* g2_b    = (const float*)d_in[22];
  const float* g2_m    = (const float*)d_in[23];
  const float* g2_v    = (const float*)d_in[24];
  const float* heads_w = (const float*)d_in[25];
  float* out = (float*)d_out;
  (void)in_sizes; (void)n_in; (void)out_size; (void)ws_size;

  char* w = (char*)d_ws;
  size_t off = 0;
  auto take = [&](size_t bytes) {
    char* p = w + off;
    off = (off + bytes + 255) & ~(size_t)255;
    return p;
  };
  bf16* pwT = (bf16*)take(512 * 256 * 2);
  bf16* pwP = (bf16*)take(512 * 256 * 2);
  bf16* pwG = (bf16*)take(2048 * 256 * 2);
  float* bnscl = (float*)take(2048 * 4);
  float* bnsft = (float*)take(2048 * 4);
  bf16* hT  = (bf16*)take((size_t)8 * 3136 * 256 * 2);
  bf16* hP  = (bf16*)take((size_t)8 * 3136 * 256 * 2);
  bf16* hG  = (bf16*)take((size_t)8 * 3136 * 256 * 2);
  bf16* th  = (bf16*)take((size_t)8 * 512 * 3136 * 2);
  bf16* ph  = (bf16*)take((size_t)8 * 512 * 3136 * 2);
  bf16* gg  = (bf16*)take((size_t)8 * 3136 * 2048 * 2);
  float* adj_raw = (float*)take(1024 * 16 * 4);
  float* adj     = (float*)take(1024 * 16 * 4);
  float* hf      = (float*)take(1024 * 4);
  float* attn    = (float*)take(1024 * 4);
  bf16* ztmp = hT;  // hT dead after gemm_op theta

  hipMemsetAsync(adj_raw, 0, 1024 * 16 * 4, stream);
  hipMemsetAsync(hf, 0, 1024 * 4, stream);

  cvt_pw_kernel<<<2048, 256, 0, stream>>>(t_pw, p_pw, g_pw, g2_g, g2_b, g2_m, g2_v,
                                          pwT, pwP, pwG, bnscl, bnsft);
  conv_kernel<<<512, 256, 0, stream>>>(x, t_dw, t_g, t_b, t_m, t_v,
                                       p_dw, p_g, p_b, p_m, p_v,
                                       g_dw, g_g, g_b, g_m, g_v, hT, hP, hG);
  gemm_op_kernel<<<dim3(4, 49, 8), 256, 0, stream>>>(pwT, hT, th, t_pb);
  gemm_op_kernel<<<dim3(4, 49, 8), 256, 0, stream>>>(pwP, hP, ph, p_pb);
  gemm_g_kernel<<<dim3(49, 16, 8), 256, 0, stream>>>(hG, pwG, gg, bnscl, bnsft);
  adj_accum_kernel<<<512, 256, 0, stream>>>(th, ph, adj_raw);
  adj_softmax_kernel<<<4, 256, 0, stream>>>(adj_raw, adj);
  consume_kernel<0><<<dim3(196, 2, 8), 256, 0, stream>>>(gg, adj, nullptr, hf, nullptr);
  attn_kernel<<<1, 128, 0, stream>>>(hf, heads_w, attn);
  consume_kernel<1><<<dim3(196, 2, 8), 256, 0, stream>>>(gg, adj, attn, nullptr, ztmp);
  zres_kernel<<<dim3(49, 4, 8), 256, 0, stream>>>(ztmp, x, out);
}

// Round 6
// 442.981 us; speedup vs baseline: 1.5155x; 1.0215x over previous
//
#include <hip/hip_runtime.h>
#include <hip/hip_bf16.h>

typedef __hip_bfloat16 bf16;
typedef __attribute__((ext_vector_type(4))) float f32x4;
typedef __attribute__((ext_vector_type(8))) short s16x8;

#define DEV static __device__ __forceinline__

namespace {

constexpr float kEPS = 1e-5f;
constexpr float kFACTOR = 1.0f / 112.0f;  // 1/sqrt(196*64)

DEV float hswish_f(float v) { return v * fminf(fmaxf(v + 3.f, 0.f), 6.f) * (1.f / 6.f); }

DEV void gload_lds16(const bf16* g, bf16* l) {
  __builtin_amdgcn_global_load_lds(
      (const __attribute__((address_space(1))) unsigned int*)g,
      (__attribute__((address_space(3))) unsigned int*)l, 16, 0, 0);
}

// ---- K0: convert pointwise weights fp32 -> bf16 (+ reorder G to c*8+h rows,
//          precompute bn2 scale/shift in storage order) ---------------------
__global__ void cvt_pw_kernel(const float* __restrict__ a,
                              const float* __restrict__ b,
                              const float* __restrict__ cG,
                              const float* __restrict__ g2g, const float* __restrict__ g2b,
                              const float* __restrict__ g2m, const float* __restrict__ g2v,
                              bf16* __restrict__ oa, bf16* __restrict__ ob,
                              bf16* __restrict__ oc, float* __restrict__ bnscl,
                              float* __restrict__ bnsft) {
  int i = blockIdx.x * 256 + threadIdx.x;
  if (i < 512 * 256) {
    oa[i] = __float2bfloat16(a[i]);
    ob[i] = __float2bfloat16(b[i]);
  }
  if (i < 2048 * 256) {
    int r = i >> 8, k = i & 255;          // ref row r = h*256+c
    int h = r >> 8, c = r & 255;
    oc[(c * 8 + h) * 256 + k] = __float2bfloat16(cG[i]);
  }
  if (i < 2048) {                         // storage o = c*8+h
    int c = i >> 3, h = i & 7, ref = h * 256 + c;
    float s = g2g[ref] * rsqrtf(g2v[ref] + kEPS);
    bnscl[i] = s;
    bnsft[i] = g2b[ref] - g2m[ref] * s;
  }
}

// ---- K1: depthwise conv(1,3,3)+BN+hswish, 3 branches ---------------------
__global__ __launch_bounds__(256) void conv_kernel(
    const float* __restrict__ x,
    const float* __restrict__ tdw, const float* __restrict__ tg,
    const float* __restrict__ tb, const float* __restrict__ tm, const float* __restrict__ tv,
    const float* __restrict__ pdw, const float* __restrict__ pg,
    const float* __restrict__ pb, const float* __restrict__ pm, const float* __restrict__ pv,
    const float* __restrict__ gdw, const float* __restrict__ gG,
    const float* __restrict__ gb, const float* __restrict__ gm, const float* __restrict__ gv,
    bf16* __restrict__ h_t, bf16* __restrict__ h_p, bf16* __restrict__ h_g) {
  int bid = blockIdx.x;
  int cb = bid & 3, t = (bid >> 2) & 15, n = bid >> 6;
  int c0 = cb * 64;
  __shared__ float xs[64][197];
  __shared__ float wts[3][64][9];
  __shared__ float sc[3][64], sh[3][64];
  int tid = threadIdx.x;
  for (int i = tid; i < 64 * 9; i += 256) {
    int cl = i / 9, k = i % 9;
    wts[0][cl][k] = tdw[(c0 + cl) * 9 + k];
    wts[1][cl][k] = pdw[(c0 + cl) * 9 + k];
    wts[2][cl][k] = gdw[(c0 + cl) * 9 + k];
  }
  if (tid < 64) {
    int c = c0 + tid;
    float s0 = tg[c] * rsqrtf(tv[c] + kEPS);
    sc[0][tid] = s0; sh[0][tid] = tb[c] - tm[c] * s0;
    float s1 = pg[c] * rsqrtf(pv[c] + kEPS);
    sc[1][tid] = s1; sh[1][tid] = pb[c] - pm[c] * s1;
    float s2 = gG[c] * rsqrtf(gv[c] + kEPS);
    sc[2][tid] = s2; sh[2][tid] = gb[c] - gm[c] * s2;
  }
  const float* xb = x + ((size_t)(n * 256 + c0) * 16 + t) * 196;
  for (int i = tid; i < 64 * 196; i += 256) {
    int cl = i / 196, s = i % 196;
    xs[cl][s] = xb[(size_t)cl * 3136 + s];
  }
  __syncthreads();
  for (int i = tid; i < 64 * 196; i += 256) {
    int cl = i & 63, sp = i >> 6;
    int hs = sp / 14, wsp = sp % 14;
    float a0 = 0.f, a1 = 0.f, a2 = 0.f;
    #pragma unroll
    for (int dy = -1; dy <= 1; ++dy) {
      int yy = hs + dy;
      if (yy < 0 || yy >= 14) continue;
      #pragma unroll
      for (int dx = -1; dx <= 1; ++dx) {
        int xx = wsp + dx;
        if (xx < 0 || xx >= 14) continue;
        float v = xs[cl][yy * 14 + xx];
        int k = (dy + 1) * 3 + (dx + 1);
        a0 = fmaf(wts[0][cl][k], v, a0);
        a1 = fmaf(wts[1][cl][k], v, a1);
        a2 = fmaf(wts[2][cl][k], v, a2);
      }
    }
    a0 = hswish_f(a0 * sc[0][cl] + sh[0][cl]);
    a1 = hswish_f(a1 * sc[1][cl] + sh[1][cl]);
    a2 = hswish_f(a2 * sc[2][cl] + sh[2][cl]);
    size_t oidx = ((size_t)n * 3136 + t * 196 + sp) * 256 + c0 + cl;
    h_t[oidx] = __float2bfloat16(a0);
    h_p[oidx] = __float2bfloat16(a1);
    h_g[oidx] = __float2bfloat16(a2);
  }
}

// ---- K2a: bf16 MFMA GEMM  D[n][o][ts] = sum_c W[o][c]*H[ts][c] + bias ----
// Epilogue: stage C tile in LDS, write full 128B lines.
__global__ __launch_bounds__(256) void gemm_op_kernel(
    const bf16* __restrict__ A,  // W [512][256]
    const bf16* __restrict__ B,  // H [8][3136][256]
    bf16* __restrict__ D,        // [8][512][3136]
    const float* __restrict__ bias) {
  int mt = blockIdx.x, nt = blockIdx.y, n = blockIdx.z;
  __shared__ __align__(16) bf16 lds_a[128 * 64];   // 16 KB; reused as C tile
  __shared__ __align__(16) bf16 lds_b[64 * 64];
  int tid = threadIdx.x;
  int wid = tid >> 6, lane = tid & 63;
  int wr = wid >> 1, wc = wid & 1;
  int l15 = lane & 15, lh = lane >> 4;
  f32x4 acc[4][2];
  #pragma unroll
  for (int m = 0; m < 4; ++m)
    #pragma unroll
    for (int q = 0; q < 2; ++q) acc[m][q] = (f32x4){0.f, 0.f, 0.f, 0.f};
  const bf16* Ab = A + (size_t)mt * 128 * 256;
  const bf16* Bb = B + ((size_t)n * 3136 + (size_t)nt * 64) * 256;
  for (int k0 = 0; k0 < 256; k0 += 64) {
    #pragma unroll
    for (int it = 0; it < 4; ++it) {
      int g = tid + it * 256;
      int row = g >> 3, c16 = g & 7;
      int4 v = *(const int4*)(Ab + (size_t)row * 256 + k0 + c16 * 8);
      *(int4*)((char*)lds_a + row * 128 + ((c16 * 16) ^ ((row & 7) << 4))) = v;
    }
    #pragma unroll
    for (int it = 0; it < 2; ++it) {
      int g = tid + it * 256;
      int row = g >> 3, c16 = g & 7;
      int4 v = *(const int4*)(Bb + (size_t)row * 256 + k0 + c16 * 8);
      *(int4*)((char*)lds_b + row * 128 + ((c16 * 16) ^ ((row & 7) << 4))) = v;
    }
    __syncthreads();
    #pragma unroll
    for (int kk = 0; kk < 64; kk += 32) {
      s16x8 af[4], bfr[2];
      #pragma unroll
      for (int m = 0; m < 4; ++m) {
        int row = wr * 64 + m * 16 + l15;
        af[m] = *(const s16x8*)((const char*)lds_a + row * 128 +
                                (((kk + lh * 8) * 2) ^ ((row & 7) << 4)));
      }
      #pragma unroll
      for (int q = 0; q < 2; ++q) {
        int row = wc * 32 + q * 16 + l15;
        bfr[q] = *(const s16x8*)((const char*)lds_b + row * 128 +
                                 (((kk + lh * 8) * 2) ^ ((row & 7) << 4)));
      }
      #pragma unroll
      for (int m = 0; m < 4; ++m)
        #pragma unroll
        for (int q = 0; q < 2; ++q)
          acc[m][q] = __builtin_amdgcn_mfma_f32_16x16x32_bf16(af[m], bfr[q], acc[m][q], 0, 0, 0);
    }
    __syncthreads();
  }
  // ---- epilogue: acc -> LDS [128 orow][64 col] swizzled, then full lines --
  #pragma unroll
  for (int m = 0; m < 4; ++m) {
    #pragma unroll
    for (int q = 0; q < 2; ++q) {
      int col = wc * 32 + q * 16 + l15;
      #pragma unroll
      for (int r = 0; r < 4; ++r) {
        int row = wr * 64 + m * 16 + lh * 4 + r;
        float v = acc[m][q][r] + bias[mt * 128 + row];
        *(bf16*)((char*)lds_a + row * 128 + ((col * 2) ^ ((row & 7) << 4))) =
            __float2bfloat16(v);
      }
    }
  }
  __syncthreads();
  #pragma unroll
  for (int it = 0; it < 4; ++it) {
    int g = tid + it * 256;            // 1024 granules of 16B: 128 rows x 8
    int row = g >> 3, cq = g & 7;
    int4 v = *(const int4*)((const char*)lds_a + row * 128 + ((cq * 16) ^ ((row & 7) << 4)));
    *(int4*)(D + ((size_t)n * 512 + mt * 128 + row) * 3136 + nt * 64 + cq * 8) = v;
  }
}

// ---- K2b: g-branch GEMM, m97 structure ------------------------------------
// D[n][ts][o] = bn2+hswish(sum_c H[ts][c]*W[o][c]); tile 64ts x 256o, BK=64.
// global_load_lds(16B) staging with pre-swizzled global source + linear LDS
// dest; XCD-chunked 1D grid (n = bid&7 -> one n per XCD, hG+W fit in L2).
__global__ __launch_bounds__(256) void gemm_g_kernel(
    const bf16* __restrict__ A,   // hG [8][3136][256]
    const bf16* __restrict__ W,   // pwG [2048][256]
    bf16* __restrict__ D,         // gg [8][3136][2048]
    const float* __restrict__ bnscl, const float* __restrict__ bnsft) {
  int bid = blockIdx.x;
  int n = bid & 7, rem = bid >> 3;
  int otb = rem / 49, tsb = rem % 49;
  __shared__ __align__(16) bf16 lds_a[64 * 64];    // 8 KB
  __shared__ __align__(16) bf16 lds_b[256 * 64];   // 32 KB; reused as C tile
  int tid = threadIdx.x;
  int wid = tid >> 6, lane = tid & 63;
  int l15 = lane & 15, lh = lane >> 4;
  f32x4 acc[4][4];
  #pragma unroll
  for (int m = 0; m < 4; ++m)
    #pragma unroll
    for (int q = 0; q < 4; ++q) acc[m][q] = (f32x4){0.f, 0.f, 0.f, 0.f};
  const bf16* Ab = A + ((size_t)n * 3136 + (size_t)tsb * 64) * 256;
  const bf16* Wb = W + (size_t)otb * 256 * 256;
  // A granule coords (64 rows x 8), B granule coords (256 rows x 8)
  int arow = tid >> 3, ac16 = tid & 7;
  for (int k0 = 0; k0 < 256; k0 += 64) {
    // A: 512 granules, linear LDS dest, source granule pre-swizzled
    #pragma unroll
    for (int it = 0; it < 2; ++it) {
      int row = arow + it * 32;
      gload_lds16(Ab + (size_t)row * 256 + k0 + ((ac16 ^ (row & 7)) * 8),
                  lds_a + (size_t)(row * 8 + ac16) * 8);
    }
    // B: 2048 granules
    #pragma unroll
    for (int it = 0; it < 8; ++it) {
      int row = arow + it * 32;
      gload_lds16(Wb + (size_t)row * 256 + k0 + ((ac16 ^ (row & 7)) * 8),
                  lds_b + (size_t)(row * 8 + ac16) * 8);
    }
    __syncthreads();
    #pragma unroll
    for (int kk = 0; kk < 64; kk += 32) {
      s16x8 af[4], bfr[4];
      #pragma unroll
      for (int m = 0; m < 4; ++m) {
        int row = m * 16 + l15;
        af[m] = *(const s16x8*)((const char*)lds_a + row * 128 +
                                (((kk + lh * 8) * 2) ^ ((row & 7) << 4)));
      }
      #pragma unroll
      for (int q = 0; q < 4; ++q) {
        int row = wid * 64 + q * 16 + l15;
        bfr[q] = *(const s16x8*)((const char*)lds_b + row * 128 +
                                 (((kk + lh * 8) * 2) ^ ((row & 7) << 4)));
      }
      #pragma unroll
      for (int m = 0; m < 4; ++m)
        #pragma unroll
        for (int q = 0; q < 4; ++q)
          acc[m][q] = __builtin_amdgcn_mfma_f32_16x16x32_bf16(af[m], bfr[q], acc[m][q], 0, 0, 0);
    }
    __syncthreads();
  }
  // ---- epilogue: acc -> LDS C tile [64 ts][256 o] (row stride 512B) -------
  #pragma unroll
  for (int q = 0; q < 4; ++q) {
    int ocol = wid * 64 + q * 16 + l15;
    float scl = bnscl[otb * 256 + ocol], sft = bnsft[otb * 256 + ocol];
    #pragma unroll
    for (int m = 0; m < 4; ++m) {
      #pragma unroll
      for (int r = 0; r < 4; ++r) {
        int row = m * 16 + lh * 4 + r;
        float v = hswish_f(acc[m][q][r] * scl + sft);
        *(bf16*)((char*)lds_b + row * 512 + ((ocol * 2) ^ ((row & 7) << 4))) =
            __float2bfloat16(v);
      }
    }
  }
  __syncthreads();
  #pragma unroll
  for (int it = 0; it < 8; ++it) {
    int g = tid + it * 256;            // 2048 granules: 64 rows x 32
    int row = g >> 5, cq = g & 31;
    int4 v = *(const int4*)((const char*)lds_b + row * 512 + ((cq * 16) ^ ((row & 7) << 4)));
    *(int4*)(D + ((size_t)n * 3136 + tsb * 64 + row) * 2048 + otb * 256 + cq * 8) = v;
  }
}

// ---- K3: adjacency logits, partial over e-blocks (atomicAdd) -------------
__global__ __launch_bounds__(256) void adj_accum_kernel(const bf16* __restrict__ th,
                                                        const bf16* __restrict__ ph,
                                                        float* __restrict__ adj_raw) {
  int bid = blockIdx.x;
  int eb = bid & 7, h = (bid >> 3) & 7, n = bid >> 6;
  __shared__ __align__(16) float As[16 * 196];
  __shared__ __align__(16) float Bs[16 * 196];
  int tid = threadIdx.x;
  int t = tid >> 4, u = tid & 15;
  float acc = 0.f;
  for (int e8 = 0; e8 < 8; ++e8) {
    int e = eb * 8 + e8;
    const bf16* tp = th + ((size_t)n * 512 + h * 64 + e) * 3136;
    const bf16* pp = ph + ((size_t)n * 512 + h * 64 + e) * 3136;
    __syncthreads();
    for (int i = tid; i < 3136; i += 256) {
      As[i] = __bfloat162float(tp[i]);
      Bs[i] = __bfloat162float(pp[i]);
    }
    __syncthreads();
    const float* ar = As + t * 196;
    const float* br = Bs + u * 196;
    #pragma unroll
    for (int j = 0; j < 49; ++j) {
      f32x4 a = *(const f32x4*)(ar + j * 4);
      f32x4 b = *(const f32x4*)(br + j * 4);
      acc = fmaf(a[0], b[0], acc); acc = fmaf(a[1], b[1], acc);
      acc = fmaf(a[2], b[2], acc); acc = fmaf(a[3], b[3], acc);
    }
  }
  atomicAdd(&adj_raw[((n * 8 + h) * 16 + t) * 16 + u], acc);
}

// ---- K3b: softmax over u (16), with FACTOR -------------------------------
__global__ void adj_softmax_kernel(const float* __restrict__ raw, float* __restrict__ adj) {
  int r = blockIdx.x * 256 + threadIdx.x;
  if (r >= 1024) return;
  const float* p = raw + r * 16;
  float* q = adj + r * 16;
  float v[16], mx = -1e30f;
  #pragma unroll
  for (int u = 0; u < 16; ++u) { v[u] = p[u] * kFACTOR; mx = fmaxf(mx, v[u]); }
  float s = 0.f;
  #pragma unroll
  for (int u = 0; u < 16; ++u) { v[u] = __expf(v[u] - mx); s += v[u]; }
  float inv = 1.f / s;
  #pragma unroll
  for (int u = 0; u < 16; ++u) q[u] = v[u] * inv;
}

// ---- K4/K6 unified consumer: LDS-staged gg pass --------------------------
template <int EPI>
__global__ __launch_bounds__(256) void consume_kernel(
    const bf16* __restrict__ gg, const float* __restrict__ adj,
    const float* __restrict__ attn, float* __restrict__ hf,
    bf16* __restrict__ ztmp) {
  int s = blockIdx.x, oh = blockIdx.y, n = blockIdx.z;
  __shared__ __align__(16) bf16 ggL[16][1024];   // 32 KB
  __shared__ __align__(16) float adjL[8][260];   // 8.3 KB
  __shared__ __align__(16) char aux[4096];       // zL (EPI=1) / hfp (EPI=0)
  bf16(*zL)[128] = (bf16(*)[128])aux;            // [16][128]
  float(*hfp)[8][16] = (float(*)[8][16])aux;     // [4][8][16]
  int tid = threadIdx.x;
  int h = tid & 7;
  for (int i = tid; i < 2048; i += 256) adjL[i >> 8][i & 255] = adj[n * 2048 + i];
  const bf16* gsrc = gg + ((size_t)n * 3136 + s) * 2048 + oh * 1024;
  #pragma unroll
  for (int u = 0; u < 16; ++u)
    *(int2*)&ggL[u][tid * 4] = *(const int2*)(gsrc + (size_t)u * 196 * 2048 + tid * 4);
  float atn[16];
  if (EPI == 1) {
    #pragma unroll
    for (int t = 0; t < 16; ++t) atn[t] = attn[n * 128 + t * 8 + h];
  }
  __syncthreads();
  float hacc[16];
  if (EPI == 0) {
    #pragma unroll
    for (int t = 0; t < 16; ++t) hacc[t] = 0.f;
  }
  #pragma unroll
  for (int tb = 0; tb < 4; ++tb) {
    f32x4 aj[4][4];
    #pragma unroll
    for (int tt = 0; tt < 4; ++tt)
      #pragma unroll
      for (int u4 = 0; u4 < 4; ++u4)
        aj[tt][u4] = *(const f32x4*)&adjL[h][(tb * 4 + tt) * 16 + u4 * 4];
    #pragma unroll
    for (int k = 0; k < 4; ++k) {
      int op = tid + k * 256;
      float gv[16];
      #pragma unroll
      for (int u = 0; u < 16; ++u) gv[u] = __bfloat162float(ggL[u][op]);
      float zp[4];
      #pragma unroll
      for (int tt = 0; tt < 4; ++tt) {
        float z = 0.f;
        #pragma unroll
        for (int u4 = 0; u4 < 4; ++u4) {
          z = fmaf(aj[tt][u4][0], gv[u4 * 4 + 0], z);
          z = fmaf(aj[tt][u4][1], gv[u4 * 4 + 1], z);
          z = fmaf(aj[tt][u4][2], gv[u4 * 4 + 2], z);
          z = fmaf(aj[tt][u4][3], gv[u4 * 4 + 3], z);
        }
        if (EPI == 0) hacc[tb * 4 + tt] += hswish_f(z);
        else zp[tt] = atn[tb * 4 + tt] * hswish_f(z);
      }
      if (EPI == 1) {
        #pragma unroll
        for (int tt = 0; tt < 4; ++tt) {
          zp[tt] += __shfl_xor(zp[tt], 1);
          zp[tt] += __shfl_xor(zp[tt], 2);
          zp[tt] += __shfl_xor(zp[tt], 4);
        }
        if (h < 4)
          zL[tb * 4 + h][(tid >> 3) + k * 32] = __float2bfloat16(zp[h]);
      }
    }
  }
  if (EPI == 0) {
    #pragma unroll
    for (int t = 0; t < 16; ++t) {
      hacc[t] += __shfl_xor(hacc[t], 8);
      hacc[t] += __shfl_xor(hacc[t], 16);
      hacc[t] += __shfl_xor(hacc[t], 32);
    }
    if ((tid & 63) < 8) {
      #pragma unroll
      for (int t = 0; t < 16; ++t) hfp[tid >> 6][h][t] = hacc[t];
    }
    __syncthreads();
    if (tid < 128) {
      int h2 = tid & 7, t2 = tid >> 3;
      float v = hfp[0][h2][t2] + hfp[1][h2][t2] + hfp[2][h2][t2] + hfp[3][h2][t2];
      atomicAdd(&hf[n * 128 + t2 * 8 + h2], v);
    }
  } else {
    __syncthreads();
    int t = tid >> 4, cq = tid & 15;
    int4 v = *(const int4*)&zL[t][cq * 8];
    *(int4*)(ztmp + ((size_t)n * 3136 + t * 196 + s) * 256 + oh * 128 + cq * 8) = v;
  }
}

// ---- K5: head-mix attn = softmax(hf_mean @ heads_w) ----------------------
__global__ void attn_kernel(const float* __restrict__ hf, const float* __restrict__ hw,
                            float* __restrict__ attn) {
  int tid = threadIdx.x;
  if (tid >= 128) return;
  int n = tid >> 4, t = tid & 15;
  const float inv = 1.0f / (256.0f * 196.0f);
  float hm[8];
  #pragma unroll
  for (int h = 0; h < 8; ++h) hm[h] = hf[(n * 16 + t) * 8 + h] * inv;
  float o[8], mx = -1e30f;
  #pragma unroll
  for (int h2 = 0; h2 < 8; ++h2) {
    float s = 0.f;
    #pragma unroll
    for (int h = 0; h < 8; ++h) s = fmaf(hm[h], hw[h * 8 + h2], s);
    o[h2] = s; mx = fmaxf(mx, s);
  }
  float s = 0.f;
  #pragma unroll
  for (int h2 = 0; h2 < 8; ++h2) { o[h2] = __expf(o[h2] - mx); s += o[h2]; }
  float is = 1.f / s;
  #pragma unroll
  for (int h2 = 0; h2 < 8; ++h2) attn[(n * 16 + t) * 8 + h2] = o[h2] * is;
}

// ---- K7: transpose z [ts][c]->[c][ts], add residual, final hswish --------
__global__ __launch_bounds__(256) void zres_kernel(const bf16* __restrict__ ztmp,
                                                   const float* __restrict__ x,
                                                   float* __restrict__ out) {
  int tsb = blockIdx.x, cb = blockIdx.y, n = blockIdx.z;
  __shared__ __align__(16) bf16 tile[64 * 64];
  int tid = threadIdx.x;
  #pragma unroll
  for (int it = 0; it < 2; ++it) {
    int g = tid + it * 256;
    int row = g >> 3, cq = g & 7;
    int4 v = *(const int4*)(ztmp + ((size_t)n * 3136 + tsb * 64 + row) * 256 + cb * 64 + cq * 8);
    *(int4*)((char*)tile + row * 128 + ((cq * 16) ^ ((row & 7) << 4))) = v;
  }
  __syncthreads();
  int cl = tid & 63, tq = tid >> 6;
  size_t obase = ((size_t)(n * 256 + cb * 64 + cl)) * 3136 + tsb * 64 + tq * 16;
  #pragma unroll
  for (int i = 0; i < 16; i += 4) {
    f32x4 xv = *(const f32x4*)(x + obase + i);
    f32x4 r;
    #pragma unroll
    for (int j = 0; j < 4; ++j) {
      int row = tq * 16 + i + j;
      unsigned short zb = *(const unsigned short*)((const char*)tile + row * 128 +
                                                   ((cl * 2) ^ ((row & 7) << 4)));
      float z = __uint_as_float((unsigned)zb << 16);
      r[j] = hswish_f(xv[j] + z);
    }
    *(f32x4*)(out + obase + i) = r;
  }
}

}  // namespace

extern "C" void kernel_launch(void* const* d_in, const int* in_sizes, int n_in,
                              void* d_out, int out_size, void* d_ws, size_t ws_size,
                              hipStream_t stream) {
  const float* x       = (const float*)d_in[0];
  const float* t_dw    = (const float*)d_in[1];
  const float* t_g     = (const float*)d_in[2];
  const float* t_b     = (const float*)d_in[3];
  const float* t_m     = (const float*)d_in[4];
  const float* t_v     = (const float*)d_in[5];
  const float* t_pw    = (const float*)d_in[6];
  const float* p_dw    = (const float*)d_in[7];
  const float* p_g     = (const float*)d_in[8];
  const float* p_b     = (const float*)d_in[9];
  const float* p_m     = (const float*)d_in[10];
  const float* p_v     = (const float*)d_in[11];
  const float* p_pw    = (const float*)d_in[12];
  const float* g_dw    = (const float*)d_in[13];
  const float* g_g     = (const float*)d_in[14];
  const float* g_b     = (const float*)d_in[15];
  const float* g_m     = (const float*)d_in[16];
  const float* g_v     = (const float*)d_in[17];
  const float* g_pw    = (const float*)d_in[18];
  const float* t_pb    = (const float*)d_in[19];
  const float* p_pb    = (const float*)d_in[20];
  const float* g2_g    = (const float*)d_in[21];
  const float* g2_b    = (const float*)d_in[22];
  const float* g2_m    = (const float*)d_in[23];
  const float* g2_v    = (const float*)d_in[24];
  const float* heads_w = (const float*)d_in[25];
  float* out = (float*)d_out;
  (void)in_sizes; (void)n_in; (void)out_size; (void)ws_size;

  char* w = (char*)d_ws;
  size_t off = 0;
  auto take = [&](size_t bytes) {
    char* p = w + off;
    off = (off + bytes + 255) & ~(size_t)255;
    return p;
  };
  bf16* pwT = (bf16*)take(512 * 256 * 2);
  bf16* pwP = (bf16*)take(512 * 256 * 2);
  bf16* pwG = (bf16*)take(2048 * 256 * 2);
  float* bnscl = (float*)take(2048 * 4);
  float* bnsft = (float*)take(2048 * 4);
  bf16* hT  = (bf16*)take((size_t)8 * 3136 * 256 * 2);
  bf16* hP  = (bf16*)take((size_t)8 * 3136 * 256 * 2);
  bf16* hG  = (bf16*)take((size_t)8 * 3136 * 256 * 2);
  bf16* th  = (bf16*)take((size_t)8 * 512 * 3136 * 2);
  bf16* ph  = (bf16*)take((size_t)8 * 512 * 3136 * 2);
  bf16* gg  = (bf16*)take((size_t)8 * 3136 * 2048 * 2);
  float* adj_raw = (float*)take(1024 * 16 * 4);
  float* adj     = (float*)take(1024 * 16 * 4);
  float* hf      = (float*)take(1024 * 4);
  float* attn    = (float*)take(1024 * 4);
  bf16* ztmp = hT;  // hT dead after gemm_op theta

  hipMemsetAsync(adj_raw, 0, 1024 * 16 * 4, stream);
  hipMemsetAsync(hf, 0, 1024 * 4, stream);

  cvt_pw_kernel<<<2048, 256, 0, stream>>>(t_pw, p_pw, g_pw, g2_g, g2_b, g2_m, g2_v,
                                          pwT, pwP, pwG, bnscl, bnsft);
  conv_kernel<<<512, 256, 0, stream>>>(x, t_dw, t_g, t_b, t_m, t_v,
                                       p_dw, p_g, p_b, p_m, p_v,
                                       g_dw, g_g, g_b, g_m, g_v, hT, hP, hG);
  gemm_op_kernel<<<dim3(4, 49, 8), 256, 0, stream>>>(pwT, hT, th, t_pb);
  gemm_op_kernel<<<dim3(4, 49, 8), 256, 0, stream>>>(pwP, hP, ph, p_pb);
  gemm_g_kernel<<<3136, 256, 0, stream>>>(hG, pwG, gg, bnscl, bnsft);
  adj_accum_kernel<<<512, 256, 0, stream>>>(th, ph, adj_raw);
  adj_softmax_kernel<<<4, 256, 0, stream>>>(adj_raw, adj);
  consume_kernel<0><<<dim3(196, 2, 8), 256, 0, stream>>>(gg, adj, nullptr, hf, nullptr);
  attn_kernel<<<1, 128, 0, stream>>>(hf, heads_w, attn);
  consume_kernel<1><<<dim3(196, 2, 8), 256, 0, stream>>>(gg, adj, attn, nullptr, ztmp);
  zres_kernel<<<dim3(49, 4, 8), 256, 0, stream>>>(ztmp, x, out);
}

// Round 7
// 432.070 us; speedup vs baseline: 1.5538x; 1.0253x over previous
//
#include <hip/hip_runtime.h>
#include <hip/hip_bf16.h>

typedef __hip_bfloat16 bf16;
typedef __attribute__((ext_vector_type(4))) float f32x4;
typedef __attribute__((ext_vector_type(8))) short s16x8;

#define DEV static __device__ __forceinline__

namespace {

constexpr float kEPS = 1e-5f;
constexpr float kFACTOR = 1.0f / 112.0f;  // 1/sqrt(196*64)

DEV float hswish_f(float v) { return v * fminf(fmaxf(v + 3.f, 0.f), 6.f) * (1.f / 6.f); }

DEV void gload_lds16(const bf16* g, bf16* l) {
  __builtin_amdgcn_global_load_lds(
      (const __attribute__((address_space(1))) unsigned int*)g,
      (__attribute__((address_space(3))) unsigned int*)l, 16, 0, 0);
}

// ---- K0: convert pointwise weights fp32 -> bf16 (+ reorder G to c*8+h rows,
//          precompute bn2 scale/shift in storage order) ---------------------
__global__ void cvt_pw_kernel(const float* __restrict__ a,
                              const float* __restrict__ b,
                              const float* __restrict__ cG,
                              const float* __restrict__ g2g, const float* __restrict__ g2b,
                              const float* __restrict__ g2m, const float* __restrict__ g2v,
                              bf16* __restrict__ oa, bf16* __restrict__ ob,
                              bf16* __restrict__ oc, float* __restrict__ bnscl,
                              float* __restrict__ bnsft) {
  int i = blockIdx.x * 256 + threadIdx.x;
  if (i < 512 * 256) {
    oa[i] = __float2bfloat16(a[i]);
    ob[i] = __float2bfloat16(b[i]);
  }
  if (i < 2048 * 256) {
    int r = i >> 8, k = i & 255;          // ref row r = h*256+c
    int h = r >> 8, c = r & 255;
    oc[(c * 8 + h) * 256 + k] = __float2bfloat16(cG[i]);
  }
  if (i < 2048) {                         // storage o = c*8+h
    int c = i >> 3, h = i & 7, ref = h * 256 + c;
    float s = g2g[ref] * rsqrtf(g2v[ref] + kEPS);
    bnscl[i] = s;
    bnsft[i] = g2b[ref] - g2m[ref] * s;
  }
}

// ---- K1: depthwise conv(1,3,3)+BN+hswish, 3 branches ---------------------
__global__ __launch_bounds__(256) void conv_kernel(
    const float* __restrict__ x,
    const float* __restrict__ tdw, const float* __restrict__ tg,
    const float* __restrict__ tb, const float* __restrict__ tm, const float* __restrict__ tv,
    const float* __restrict__ pdw, const float* __restrict__ pg,
    const float* __restrict__ pb, const float* __restrict__ pm, const float* __restrict__ pv,
    const float* __restrict__ gdw, const float* __restrict__ gG,
    const float* __restrict__ gb, const float* __restrict__ gm, const float* __restrict__ gv,
    bf16* __restrict__ h_t, bf16* __restrict__ h_p, bf16* __restrict__ h_g) {
  int bid = blockIdx.x;
  int cb = bid & 3, t = (bid >> 2) & 15, n = bid >> 6;
  int c0 = cb * 64;
  __shared__ float xs[64][197];
  __shared__ float wts[3][64][9];
  __shared__ float sc[3][64], sh[3][64];
  int tid = threadIdx.x;
  for (int i = tid; i < 64 * 9; i += 256) {
    int cl = i / 9, k = i % 9;
    wts[0][cl][k] = tdw[(c0 + cl) * 9 + k];
    wts[1][cl][k] = pdw[(c0 + cl) * 9 + k];
    wts[2][cl][k] = gdw[(c0 + cl) * 9 + k];
  }
  if (tid < 64) {
    int c = c0 + tid;
    float s0 = tg[c] * rsqrtf(tv[c] + kEPS);
    sc[0][tid] = s0; sh[0][tid] = tb[c] - tm[c] * s0;
    float s1 = pg[c] * rsqrtf(pv[c] + kEPS);
    sc[1][tid] = s1; sh[1][tid] = pb[c] - pm[c] * s1;
    float s2 = gG[c] * rsqrtf(gv[c] + kEPS);
    sc[2][tid] = s2; sh[2][tid] = gb[c] - gm[c] * s2;
  }
  const float* xb = x + ((size_t)(n * 256 + c0) * 16 + t) * 196;
  for (int i = tid; i < 64 * 196; i += 256) {
    int cl = i / 196, s = i % 196;
    xs[cl][s] = xb[(size_t)cl * 3136 + s];
  }
  __syncthreads();
  for (int i = tid; i < 64 * 196; i += 256) {
    int cl = i & 63, sp = i >> 6;
    int hs = sp / 14, wsp = sp % 14;
    float a0 = 0.f, a1 = 0.f, a2 = 0.f;
    #pragma unroll
    for (int dy = -1; dy <= 1; ++dy) {
      int yy = hs + dy;
      if (yy < 0 || yy >= 14) continue;
      #pragma unroll
      for (int dx = -1; dx <= 1; ++dx) {
        int xx = wsp + dx;
        if (xx < 0 || xx >= 14) continue;
        float v = xs[cl][yy * 14 + xx];
        int k = (dy + 1) * 3 + (dx + 1);
        a0 = fmaf(wts[0][cl][k], v, a0);
        a1 = fmaf(wts[1][cl][k], v, a1);
        a2 = fmaf(wts[2][cl][k], v, a2);
      }
    }
    a0 = hswish_f(a0 * sc[0][cl] + sh[0][cl]);
    a1 = hswish_f(a1 * sc[1][cl] + sh[1][cl]);
    a2 = hswish_f(a2 * sc[2][cl] + sh[2][cl]);
    size_t oidx = ((size_t)n * 3136 + t * 196 + sp) * 256 + c0 + cl;
    h_t[oidx] = __float2bfloat16(a0);
    h_p[oidx] = __float2bfloat16(a1);
    h_g[oidx] = __float2bfloat16(a2);
  }
}

// ---- K2a: bf16 MFMA GEMM  D[n][o][ts] = sum_c W[o][c]*H[ts][c] + bias ----
// Epilogue: stage C tile in LDS, write full 128B lines.
__global__ __launch_bounds__(256) void gemm_op_kernel(
    const bf16* __restrict__ A,  // W [512][256]
    const bf16* __restrict__ B,  // H [8][3136][256]
    bf16* __restrict__ D,        // [8][512][3136]
    const float* __restrict__ bias) {
  int mt = blockIdx.x, nt = blockIdx.y, n = blockIdx.z;
  __shared__ __align__(16) bf16 lds_a[128 * 64];   // 16 KB; reused as C tile
  __shared__ __align__(16) bf16 lds_b[64 * 64];
  int tid = threadIdx.x;
  int wid = tid >> 6, lane = tid & 63;
  int wr = wid >> 1, wc = wid & 1;
  int l15 = lane & 15, lh = lane >> 4;
  f32x4 acc[4][2];
  #pragma unroll
  for (int m = 0; m < 4; ++m)
    #pragma unroll
    for (int q = 0; q < 2; ++q) acc[m][q] = (f32x4){0.f, 0.f, 0.f, 0.f};
  const bf16* Ab = A + (size_t)mt * 128 * 256;
  const bf16* Bb = B + ((size_t)n * 3136 + (size_t)nt * 64) * 256;
  for (int k0 = 0; k0 < 256; k0 += 64) {
    #pragma unroll
    for (int it = 0; it < 4; ++it) {
      int g = tid + it * 256;
      int row = g >> 3, c16 = g & 7;
      int4 v = *(const int4*)(Ab + (size_t)row * 256 + k0 + c16 * 8);
      *(int4*)((char*)lds_a + row * 128 + ((c16 * 16) ^ ((row & 7) << 4))) = v;
    }
    #pragma unroll
    for (int it = 0; it < 2; ++it) {
      int g = tid + it * 256;
      int row = g >> 3, c16 = g & 7;
      int4 v = *(const int4*)(Bb + (size_t)row * 256 + k0 + c16 * 8);
      *(int4*)((char*)lds_b + row * 128 + ((c16 * 16) ^ ((row & 7) << 4))) = v;
    }
    __syncthreads();
    #pragma unroll
    for (int kk = 0; kk < 64; kk += 32) {
      s16x8 af[4], bfr[2];
      #pragma unroll
      for (int m = 0; m < 4; ++m) {
        int row = wr * 64 + m * 16 + l15;
        af[m] = *(const s16x8*)((const char*)lds_a + row * 128 +
                                (((kk + lh * 8) * 2) ^ ((row & 7) << 4)));
      }
      #pragma unroll
      for (int q = 0; q < 2; ++q) {
        int row = wc * 32 + q * 16 + l15;
        bfr[q] = *(const s16x8*)((const char*)lds_b + row * 128 +
                                 (((kk + lh * 8) * 2) ^ ((row & 7) << 4)));
      }
      #pragma unroll
      for (int m = 0; m < 4; ++m)
        #pragma unroll
        for (int q = 0; q < 2; ++q)
          acc[m][q] = __builtin_amdgcn_mfma_f32_16x16x32_bf16(af[m], bfr[q], acc[m][q], 0, 0, 0);
    }
    __syncthreads();
  }
  // ---- epilogue: acc -> LDS [128 orow][64 col] swizzled, then full lines --
  #pragma unroll
  for (int m = 0; m < 4; ++m) {
    #pragma unroll
    for (int q = 0; q < 2; ++q) {
      int col = wc * 32 + q * 16 + l15;
      #pragma unroll
      for (int r = 0; r < 4; ++r) {
        int row = wr * 64 + m * 16 + lh * 4 + r;
        float v = acc[m][q][r] + bias[mt * 128 + row];
        *(bf16*)((char*)lds_a + row * 128 + ((col * 2) ^ ((row & 7) << 4))) =
            __float2bfloat16(v);
      }
    }
  }
  __syncthreads();
  #pragma unroll
  for (int it = 0; it < 4; ++it) {
    int g = tid + it * 256;            // 1024 granules of 16B: 128 rows x 8
    int row = g >> 3, cq = g & 7;
    int4 v = *(const int4*)((const char*)lds_a + row * 128 + ((cq * 16) ^ ((row & 7) << 4)));
    *(int4*)(D + ((size_t)n * 512 + mt * 128 + row) * 3136 + nt * 64 + cq * 8) = v;
  }
}

// ---- K2b: g-branch GEMM, m97 structure ------------------------------------
__global__ __launch_bounds__(256) void gemm_g_kernel(
    const bf16* __restrict__ A,   // hG [8][3136][256]
    const bf16* __restrict__ W,   // pwG [2048][256]
    bf16* __restrict__ D,         // gg [8][3136][2048]
    const float* __restrict__ bnscl, const float* __restrict__ bnsft) {
  int bid = blockIdx.x;
  int n = bid & 7, rem = bid >> 3;
  int otb = rem / 49, tsb = rem % 49;
  __shared__ __align__(16) bf16 lds_a[64 * 64];    // 8 KB
  __shared__ __align__(16) bf16 lds_b[256 * 64];   // 32 KB; reused as C tile
  int tid = threadIdx.x;
  int wid = tid >> 6, lane = tid & 63;
  int l15 = lane & 15, lh = lane >> 4;
  f32x4 acc[4][4];
  #pragma unroll
  for (int m = 0; m < 4; ++m)
    #pragma unroll
    for (int q = 0; q < 4; ++q) acc[m][q] = (f32x4){0.f, 0.f, 0.f, 0.f};
  const bf16* Ab = A + ((size_t)n * 3136 + (size_t)tsb * 64) * 256;
  const bf16* Wb = W + (size_t)otb * 256 * 256;
  int arow = tid >> 3, ac16 = tid & 7;
  for (int k0 = 0; k0 < 256; k0 += 64) {
    #pragma unroll
    for (int it = 0; it < 2; ++it) {
      int row = arow + it * 32;
      gload_lds16(Ab + (size_t)row * 256 + k0 + ((ac16 ^ (row & 7)) * 8),
                  lds_a + (size_t)(row * 8 + ac16) * 8);
    }
    #pragma unroll
    for (int it = 0; it < 8; ++it) {
      int row = arow + it * 32;
      gload_lds16(Wb + (size_t)row * 256 + k0 + ((ac16 ^ (row & 7)) * 8),
                  lds_b + (size_t)(row * 8 + ac16) * 8);
    }
    __syncthreads();
    #pragma unroll
    for (int kk = 0; kk < 64; kk += 32) {
      s16x8 af[4], bfr[4];
      #pragma unroll
      for (int m = 0; m < 4; ++m) {
        int row = m * 16 + l15;
        af[m] = *(const s16x8*)((const char*)lds_a + row * 128 +
                                (((kk + lh * 8) * 2) ^ ((row & 7) << 4)));
      }
      #pragma unroll
      for (int q = 0; q < 4; ++q) {
        int row = wid * 64 + q * 16 + l15;
        bfr[q] = *(const s16x8*)((const char*)lds_b + row * 128 +
                                 (((kk + lh * 8) * 2) ^ ((row & 7) << 4)));
      }
      #pragma unroll
      for (int m = 0; m < 4; ++m)
        #pragma unroll
        for (int q = 0; q < 4; ++q)
          acc[m][q] = __builtin_amdgcn_mfma_f32_16x16x32_bf16(af[m], bfr[q], acc[m][q], 0, 0, 0);
    }
    __syncthreads();
  }
  #pragma unroll
  for (int q = 0; q < 4; ++q) {
    int ocol = wid * 64 + q * 16 + l15;
    float scl = bnscl[otb * 256 + ocol], sft = bnsft[otb * 256 + ocol];
    #pragma unroll
    for (int m = 0; m < 4; ++m) {
      #pragma unroll
      for (int r = 0; r < 4; ++r) {
        int row = m * 16 + lh * 4 + r;
        float v = hswish_f(acc[m][q][r] * scl + sft);
        *(bf16*)((char*)lds_b + row * 512 + ((ocol * 2) ^ ((row & 7) << 4))) =
            __float2bfloat16(v);
      }
    }
  }
  __syncthreads();
  #pragma unroll
  for (int it = 0; it < 8; ++it) {
    int g = tid + it * 256;            // 2048 granules: 64 rows x 32
    int row = g >> 5, cq = g & 31;
    int4 v = *(const int4*)((const char*)lds_b + row * 512 + ((cq * 16) ^ ((row & 7) << 4)));
    *(int4*)(D + ((size_t)n * 3136 + tsb * 64 + row) * 2048 + otb * 256 + cq * 8) = v;
  }
}

// ---- K3: adjacency logits, partial over e-blocks (atomicAdd) -------------
__global__ __launch_bounds__(256) void adj_accum_kernel(const bf16* __restrict__ th,
                                                        const bf16* __restrict__ ph,
                                                        float* __restrict__ adj_raw) {
  int bid = blockIdx.x;
  int eb = bid & 7, h = (bid >> 3) & 7, n = bid >> 6;
  __shared__ __align__(16) float As[16 * 196];
  __shared__ __align__(16) float Bs[16 * 196];
  int tid = threadIdx.x;
  int t = tid >> 4, u = tid & 15;
  float acc = 0.f;
  for (int e8 = 0; e8 < 8; ++e8) {
    int e = eb * 8 + e8;
    const bf16* tp = th + ((size_t)n * 512 + h * 64 + e) * 3136;
    const bf16* pp = ph + ((size_t)n * 512 + h * 64 + e) * 3136;
    __syncthreads();
    for (int i = tid; i < 3136; i += 256) {
      As[i] = __bfloat162float(tp[i]);
      Bs[i] = __bfloat162float(pp[i]);
    }
    __syncthreads();
    const float* ar = As + t * 196;
    const float* br = Bs + u * 196;
    #pragma unroll
    for (int j = 0; j < 49; ++j) {
      f32x4 a = *(const f32x4*)(ar + j * 4);
      f32x4 b = *(const f32x4*)(br + j * 4);
      acc = fmaf(a[0], b[0], acc); acc = fmaf(a[1], b[1], acc);
      acc = fmaf(a[2], b[2], acc); acc = fmaf(a[3], b[3], acc);
    }
  }
  atomicAdd(&adj_raw[((n * 8 + h) * 16 + t) * 16 + u], acc);
}

// ---- K3b: softmax over u (16), with FACTOR -------------------------------
__global__ void adj_softmax_kernel(const float* __restrict__ raw, float* __restrict__ adj) {
  int r = blockIdx.x * 256 + threadIdx.x;
  if (r >= 1024) return;
  const float* p = raw + r * 16;
  float* q = adj + r * 16;
  float v[16], mx = -1e30f;
  #pragma unroll
  for (int u = 0; u < 16; ++u) { v[u] = p[u] * kFACTOR; mx = fmaxf(mx, v[u]); }
  float s = 0.f;
  #pragma unroll
  for (int u = 0; u < 16; ++u) { v[u] = __expf(v[u] - mx); s += v[u]; }
  float inv = 1.f / s;
  #pragma unroll
  for (int u = 0; u < 16; ++u) q[u] = v[u] * inv;
}

// ---- K4/K6 unified consumer: direct coalesced gg reads -------------------
// block = (s, o-half, n). Thread owns o' = tid + k*256 -> h = tid&7 fixed.
// gg reads: lane tid reads bf16 at [u*196+s][oh*1024 + tid + k*256] -> each
// wave covers one full 128B line per (u,k); 4x tb re-read served by L1/L2.
// EPI=0: hf[n][t][h] += sum_{c'} hswish(z)        (shuffle over c-lanes)
// EPI=1: ztmp[n][ts][c] = sum_h attn*hswish(z)    (shuffle over h-lanes)
template <int EPI>
__global__ __launch_bounds__(256) void consume_kernel(
    const bf16* __restrict__ gg, const float* __restrict__ adj,
    const float* __restrict__ attn, float* __restrict__ hf,
    bf16* __restrict__ ztmp) {
  int s = blockIdx.x, oh = blockIdx.y, n = blockIdx.z;
  __shared__ __align__(16) float adjL[8][260];   // 8.3 KB; 260 f32 = 65x16B
  __shared__ __align__(16) char aux[4096];       // zL (EPI=1) / hfp (EPI=0)
  bf16(*zL)[128] = (bf16(*)[128])aux;            // [16][128]
  float(*hfp)[8][16] = (float(*)[8][16])aux;     // [4][8][16]
  int tid = threadIdx.x;
  int h = tid & 7;
  for (int i = tid; i < 2048; i += 256) adjL[i >> 8][i & 255] = adj[n * 2048 + i];
  float atn[16];
  if (EPI == 1) {
    #pragma unroll
    for (int t = 0; t < 16; ++t) atn[t] = attn[n * 128 + t * 8 + h];
  }
  __syncthreads();
  const bf16* gbase = gg + ((size_t)n * 3136 + s) * 2048 + oh * 1024 + tid;
  float hacc[16];
  if (EPI == 0) {
    #pragma unroll
    for (int t = 0; t < 16; ++t) hacc[t] = 0.f;
  }
  #pragma unroll
  for (int tb = 0; tb < 4; ++tb) {
    f32x4 aj[4][4];
    #pragma unroll
    for (int tt = 0; tt < 4; ++tt)
      #pragma unroll
      for (int u4 = 0; u4 < 4; ++u4)
        aj[tt][u4] = *(const f32x4*)&adjL[h][(tb * 4 + tt) * 16 + u4 * 4];
    #pragma unroll
    for (int k = 0; k < 4; ++k) {
      const bf16* gp = gbase + k * 256;
      float gv[16];
      #pragma unroll
      for (int u = 0; u < 16; ++u)
        gv[u] = __bfloat162float(gp[(size_t)u * (196 * 2048)]);
      float zp[4];
      #pragma unroll
      for (int tt = 0; tt < 4; ++tt) {
        float z = 0.f;
        #pragma unroll
        for (int u4 = 0; u4 < 4; ++u4) {
          z = fmaf(aj[tt][u4][0], gv[u4 * 4 + 0], z);
          z = fmaf(aj[tt][u4][1], gv[u4 * 4 + 1], z);
          z = fmaf(aj[tt][u4][2], gv[u4 * 4 + 2], z);
          z = fmaf(aj[tt][u4][3], gv[u4 * 4 + 3], z);
        }
        if (EPI == 0) hacc[tb * 4 + tt] += hswish_f(z);
        else zp[tt] = atn[tb * 4 + tt] * hswish_f(z);
      }
      if (EPI == 1) {
        #pragma unroll
        for (int tt = 0; tt < 4; ++tt) {
          zp[tt] += __shfl_xor(zp[tt], 1);
          zp[tt] += __shfl_xor(zp[tt], 2);
          zp[tt] += __shfl_xor(zp[tt], 4);
        }
        if (h < 4)
          zL[tb * 4 + h][(tid >> 3) + k * 32] = __float2bfloat16(zp[h]);
      }
    }
  }
  if (EPI == 0) {
    #pragma unroll
    for (int t = 0; t < 16; ++t) {
      hacc[t] += __shfl_xor(hacc[t], 8);
      hacc[t] += __shfl_xor(hacc[t], 16);
      hacc[t] += __shfl_xor(hacc[t], 32);
    }
    if ((tid & 63) < 8) {
      #pragma unroll
      for (int t = 0; t < 16; ++t) hfp[tid >> 6][h][t] = hacc[t];
    }
    __syncthreads();
    if (tid < 128) {
      int h2 = tid & 7, t2 = tid >> 3;
      float v = hfp[0][h2][t2] + hfp[1][h2][t2] + hfp[2][h2][t2] + hfp[3][h2][t2];
      atomicAdd(&hf[n * 128 + t2 * 8 + h2], v);
    }
  } else {
    __syncthreads();
    int t = tid >> 4, cq = tid & 15;
    int4 v = *(const int4*)&zL[t][cq * 8];
    *(int4*)(ztmp + ((size_t)n * 3136 + t * 196 + s) * 256 + oh * 128 + cq * 8) = v;
  }
}

// ---- K5: head-mix attn = softmax(hf_mean @ heads_w) ----------------------
__global__ void attn_kernel(const float* __restrict__ hf, const float* __restrict__ hw,
                            float* __restrict__ attn) {
  int tid = threadIdx.x;
  if (tid >= 128) return;
  int n = tid >> 4, t = tid & 15;
  const float inv = 1.0f / (256.0f * 196.0f);
  float hm[8];
  #pragma unroll
  for (int h = 0; h < 8; ++h) hm[h] = hf[(n * 16 + t) * 8 + h] * inv;
  float o[8], mx = -1e30f;
  #pragma unroll
  for (int h2 = 0; h2 < 8; ++h2) {
    float s = 0.f;
    #pragma unroll
    for (int h = 0; h < 8; ++h) s = fmaf(hm[h], hw[h * 8 + h2], s);
    o[h2] = s; mx = fmaxf(mx, s);
  }
  float s = 0.f;
  #pragma unroll
  for (int h2 = 0; h2 < 8; ++h2) { o[h2] = __expf(o[h2] - mx); s += o[h2]; }
  float is = 1.f / s;
  #pragma unroll
  for (int h2 = 0; h2 < 8; ++h2) attn[(n * 16 + t) * 8 + h2] = o[h2] * is;
}

// ---- K7: transpose z [ts][c]->[c][ts], add residual, final hswish --------
__global__ __launch_bounds__(256) void zres_kernel(const bf16* __restrict__ ztmp,
                                                   const float* __restrict__ x,
                                                   float* __restrict__ out) {
  int tsb = blockIdx.x, cb = blockIdx.y, n = blockIdx.z;
  __shared__ __align__(16) bf16 tile[64 * 64];
  int tid = threadIdx.x;
  #pragma unroll
  for (int it = 0; it < 2; ++it) {
    int g = tid + it * 256;
    int row = g >> 3, cq = g & 7;
    int4 v = *(const int4*)(ztmp + ((size_t)n * 3136 + tsb * 64 + row) * 256 + cb * 64 + cq * 8);
    *(int4*)((char*)tile + row * 128 + ((cq * 16) ^ ((row & 7) << 4))) = v;
  }
  __syncthreads();
  int cl = tid & 63, tq = tid >> 6;
  size_t obase = ((size_t)(n * 256 + cb * 64 + cl)) * 3136 + tsb * 64 + tq * 16;
  #pragma unroll
  for (int i = 0; i < 16; i += 4) {
    f32x4 xv = *(const f32x4*)(x + obase + i);
    f32x4 r;
    #pragma unroll
    for (int j = 0; j < 4; ++j) {
      int row = tq * 16 + i + j;
      unsigned short zb = *(const unsigned short*)((const char*)tile + row * 128 +
                                                   ((cl * 2) ^ ((row & 7) << 4)));
      float z = __uint_as_float((unsigned)zb << 16);
      r[j] = hswish_f(xv[j] + z);
    }
    *(f32x4*)(out + obase + i) = r;
  }
}

}  // namespace

extern "C" void kernel_launch(void* const* d_in, const int* in_sizes, int n_in,
                              void* d_out, int out_size, void* d_ws, size_t ws_size,
                              hipStream_t stream) {
  const float* x       = (const float*)d_in[0];
  const float* t_dw    = (const float*)d_in[1];
  const float* t_g     = (const float*)d_in[2];
  const float* t_b     = (const float*)d_in[3];
  const float* t_m     = (const float*)d_in[4];
  const float* t_v     = (const float*)d_in[5];
  const float* t_pw    = (const float*)d_in[6];
  const float* p_dw    = (const float*)d_in[7];
  const float* p_g     = (const float*)d_in[8];
  const float* p_b     = (const float*)d_in[9];
  const float* p_m     = (const float*)d_in[10];
  const float* p_v     = (const float*)d_in[11];
  const float* p_pw    = (const float*)d_in[12];
  const float* g_dw    = (const float*)d_in[13];
  const float* g_g     = (const float*)d_in[14];
  const float* g_b     = (const float*)d_in[15];
  const float* g_m     = (const float*)d_in[16];
  const float* g_v     = (const float*)d_in[17];
  const float* g_pw    = (const float*)d_in[18];
  const float* t_pb    = (const float*)d_in[19];
  const float* p_pb    = (const float*)d_in[20];
  const float* g2_g    = (const float*)d_in[21];
  const float* g2_b    = (const float*)d_in[22];
  const float* g2_m    = (const float*)d_in[23];
  const float* g2_v    = (const float*)d_in[24];
  const float* heads_w = (const float*)d_in[25];
  float* out = (float*)d_out;
  (void)in_sizes; (void)n_in; (void)out_size; (void)ws_size;

  char* w = (char*)d_ws;
  size_t off = 0;
  auto take = [&](size_t bytes) {
    char* p = w + off;
    off = (off + bytes + 255) & ~(size_t)255;
    return p;
  };
  bf16* pwT = (bf16*)take(512 * 256 * 2);
  bf16* pwP = (bf16*)take(512 * 256 * 2);
  bf16* pwG = (bf16*)take(2048 * 256 * 2);
  float* bnscl = (float*)take(2048 * 4);
  float* bnsft = (float*)take(2048 * 4);
  bf16* hT  = (bf16*)take((size_t)8 * 3136 * 256 * 2);
  bf16* hP  = (bf16*)take((size_t)8 * 3136 * 256 * 2);
  bf16* hG  = (bf16*)take((size_t)8 * 3136 * 256 * 2);
  bf16* th  = (bf16*)take((size_t)8 * 512 * 3136 * 2);
  bf16* ph  = (bf16*)take((size_t)8 * 512 * 3136 * 2);
  bf16* gg  = (bf16*)take((size_t)8 * 3136 * 2048 * 2);
  float* adj_raw = (float*)take(1024 * 16 * 4);
  float* adj     = (float*)take(1024 * 16 * 4);
  float* hf      = (float*)take(1024 * 4);
  float* attn    = (float*)take(1024 * 4);
  bf16* ztmp = hT;  // hT dead after gemm_op theta

  hipMemsetAsync(adj_raw, 0, 1024 * 16 * 4, stream);
  hipMemsetAsync(hf, 0, 1024 * 4, stream);

  cvt_pw_kernel<<<2048, 256, 0, stream>>>(t_pw, p_pw, g_pw, g2_g, g2_b, g2_m, g2_v,
                                          pwT, pwP, pwG, bnscl, bnsft);
  conv_kernel<<<512, 256, 0, stream>>>(x, t_dw, t_g, t_b, t_m, t_v,
                                       p_dw, p_g, p_b, p_m, p_v,
                                       g_dw, g_g, g_b, g_m, g_v, hT, hP, hG);
  gemm_op_kernel<<<dim3(4, 49, 8), 256, 0, stream>>>(pwT, hT, th, t_pb);
  gemm_op_kernel<<<dim3(4, 49, 8), 256, 0, stream>>>(pwP, hP, ph, p_pb);
  gemm_g_kernel<<<3136, 256, 0, stream>>>(hG, pwG, gg, bnscl, bnsft);
  adj_accum_kernel<<<512, 256, 0, stream>>>(th, ph, adj_raw);
  adj_softmax_kernel<<<4, 256, 0, stream>>>(adj_raw, adj);
  consume_kernel<0><<<dim3(196, 2, 8), 256, 0, stream>>>(gg, adj, nullptr, hf, nullptr);
  attn_kernel<<<1, 128, 0, stream>>>(hf, heads_w, attn);
  consume_kernel<1><<<dim3(196, 2, 8), 256, 0, stream>>>(gg, adj, attn, nullptr, ztmp);
  zres_kernel<<<dim3(49, 4, 8), 256, 0, stream>>>(ztmp, x, out);
}

// Round 8
// 415.757 us; speedup vs baseline: 1.6147x; 1.0392x over previous
//
#include <hip/hip_runtime.h>
#include <hip/hip_bf16.h>

typedef __hip_bfloat16 bf16;
typedef __attribute__((ext_vector_type(4))) float f32x4;
typedef __attribute__((ext_vector_type(8))) short s16x8;

#define DEV static __device__ __forceinline__

namespace {

constexpr float kEPS = 1e-5f;
constexpr float kFACTOR = 1.0f / 112.0f;  // 1/sqrt(196*64)

DEV float hswish_f(float v) { return v * fminf(fmaxf(v + 3.f, 0.f), 6.f) * (1.f / 6.f); }
DEV float blo(unsigned r) { return __uint_as_float(r << 16); }
DEV float bhi(unsigned r) { return __uint_as_float(r & 0xFFFF0000u); }

DEV void gload_lds16(const bf16* g, bf16* l) {
  __builtin_amdgcn_global_load_lds(
      (const __attribute__((address_space(1))) unsigned int*)g,
      (__attribute__((address_space(3))) unsigned int*)l, 16, 0, 0);
}

// ---- K0: convert pointwise weights fp32 -> bf16 (+ reorder G to c*8+h rows,
//          precompute bn2 scale/shift in storage order) ---------------------
__global__ void cvt_pw_kernel(const float* __restrict__ a,
                              const float* __restrict__ b,
                              const float* __restrict__ cG,
                              const float* __restrict__ g2g, const float* __restrict__ g2b,
                              const float* __restrict__ g2m, const float* __restrict__ g2v,
                              bf16* __restrict__ oa, bf16* __restrict__ ob,
                              bf16* __restrict__ oc, float* __restrict__ bnscl,
                              float* __restrict__ bnsft) {
  int i = blockIdx.x * 256 + threadIdx.x;
  if (i < 512 * 256) {
    oa[i] = __float2bfloat16(a[i]);
    ob[i] = __float2bfloat16(b[i]);
  }
  if (i < 2048 * 256) {
    int r = i >> 8, k = i & 255;          // ref row r = h*256+c
    int h = r >> 8, c = r & 255;
    oc[(c * 8 + h) * 256 + k] = __float2bfloat16(cG[i]);
  }
  if (i < 2048) {                         // storage o = c*8+h
    int c = i >> 3, h = i & 7, ref = h * 256 + c;
    float s = g2g[ref] * rsqrtf(g2v[ref] + kEPS);
    bnscl[i] = s;
    bnsft[i] = g2b[ref] - g2m[ref] * s;
  }
}

// ---- K1: depthwise conv(1,3,3)+BN+hswish, 3 branches ---------------------
__global__ __launch_bounds__(256) void conv_kernel(
    const float* __restrict__ x,
    const float* __restrict__ tdw, const float* __restrict__ tg,
    const float* __restrict__ tb, const float* __restrict__ tm, const float* __restrict__ tv,
    const float* __restrict__ pdw, const float* __restrict__ pg,
    const float* __restrict__ pb, const float* __restrict__ pm, const float* __restrict__ pv,
    const float* __restrict__ gdw, const float* __restrict__ gG,
    const float* __restrict__ gb, const float* __restrict__ gm, const float* __restrict__ gv,
    bf16* __restrict__ h_t, bf16* __restrict__ h_p, bf16* __restrict__ h_g) {
  int bid = blockIdx.x;
  int cb = bid & 3, t = (bid >> 2) & 15, n = bid >> 6;
  int c0 = cb * 64;
  __shared__ float xs[64][197];
  __shared__ float wts[3][64][9];
  __shared__ float sc[3][64], sh[3][64];
  int tid = threadIdx.x;
  for (int i = tid; i < 64 * 9; i += 256) {
    int cl = i / 9, k = i % 9;
    wts[0][cl][k] = tdw[(c0 + cl) * 9 + k];
    wts[1][cl][k] = pdw[(c0 + cl) * 9 + k];
    wts[2][cl][k] = gdw[(c0 + cl) * 9 + k];
  }
  if (tid < 64) {
    int c = c0 + tid;
    float s0 = tg[c] * rsqrtf(tv[c] + kEPS);
    sc[0][tid] = s0; sh[0][tid] = tb[c] - tm[c] * s0;
    float s1 = pg[c] * rsqrtf(pv[c] + kEPS);
    sc[1][tid] = s1; sh[1][tid] = pb[c] - pm[c] * s1;
    float s2 = gG[c] * rsqrtf(gv[c] + kEPS);
    sc[2][tid] = s2; sh[2][tid] = gb[c] - gm[c] * s2;
  }
  const float* xb = x + ((size_t)(n * 256 + c0) * 16 + t) * 196;
  for (int i = tid; i < 64 * 196; i += 256) {
    int cl = i / 196, s = i % 196;
    xs[cl][s] = xb[(size_t)cl * 3136 + s];
  }
  __syncthreads();
  for (int i = tid; i < 64 * 196; i += 256) {
    int cl = i & 63, sp = i >> 6;
    int hs = sp / 14, wsp = sp % 14;
    float a0 = 0.f, a1 = 0.f, a2 = 0.f;
    #pragma unroll
    for (int dy = -1; dy <= 1; ++dy) {
      int yy = hs + dy;
      if (yy < 0 || yy >= 14) continue;
      #pragma unroll
      for (int dx = -1; dx <= 1; ++dx) {
        int xx = wsp + dx;
        if (xx < 0 || xx >= 14) continue;
        float v = xs[cl][yy * 14 + xx];
        int k = (dy + 1) * 3 + (dx + 1);
        a0 = fmaf(wts[0][cl][k], v, a0);
        a1 = fmaf(wts[1][cl][k], v, a1);
        a2 = fmaf(wts[2][cl][k], v, a2);
      }
    }
    a0 = hswish_f(a0 * sc[0][cl] + sh[0][cl]);
    a1 = hswish_f(a1 * sc[1][cl] + sh[1][cl]);
    a2 = hswish_f(a2 * sc[2][cl] + sh[2][cl]);
    size_t oidx = ((size_t)n * 3136 + t * 196 + sp) * 256 + c0 + cl;
    h_t[oidx] = __float2bfloat16(a0);
    h_p[oidx] = __float2bfloat16(a1);
    h_g[oidx] = __float2bfloat16(a2);
  }
}

// ---- K2a: bf16 MFMA GEMM  D[n][o][ts] = sum_c W[o][c]*H[ts][c] + bias ----
__global__ __launch_bounds__(256) void gemm_op_kernel(
    const bf16* __restrict__ A,  // W [512][256]
    const bf16* __restrict__ B,  // H [8][3136][256]
    bf16* __restrict__ D,        // [8][512][3136]
    const float* __restrict__ bias) {
  int mt = blockIdx.x, nt = blockIdx.y, n = blockIdx.z;
  __shared__ __align__(16) bf16 lds_a[128 * 64];   // 16 KB; reused as C tile
  __shared__ __align__(16) bf16 lds_b[64 * 64];
  int tid = threadIdx.x;
  int wid = tid >> 6, lane = tid & 63;
  int wr = wid >> 1, wc = wid & 1;
  int l15 = lane & 15, lh = lane >> 4;
  f32x4 acc[4][2];
  #pragma unroll
  for (int m = 0; m < 4; ++m)
    #pragma unroll
    for (int q = 0; q < 2; ++q) acc[m][q] = (f32x4){0.f, 0.f, 0.f, 0.f};
  const bf16* Ab = A + (size_t)mt * 128 * 256;
  const bf16* Bb = B + ((size_t)n * 3136 + (size_t)nt * 64) * 256;
  for (int k0 = 0; k0 < 256; k0 += 64) {
    #pragma unroll
    for (int it = 0; it < 4; ++it) {
      int g = tid + it * 256;
      int row = g >> 3, c16 = g & 7;
      int4 v = *(const int4*)(Ab + (size_t)row * 256 + k0 + c16 * 8);
      *(int4*)((char*)lds_a + row * 128 + ((c16 * 16) ^ ((row & 7) << 4))) = v;
    }
    #pragma unroll
    for (int it = 0; it < 2; ++it) {
      int g = tid + it * 256;
      int row = g >> 3, c16 = g & 7;
      int4 v = *(const int4*)(Bb + (size_t)row * 256 + k0 + c16 * 8);
      *(int4*)((char*)lds_b + row * 128 + ((c16 * 16) ^ ((row & 7) << 4))) = v;
    }
    __syncthreads();
    #pragma unroll
    for (int kk = 0; kk < 64; kk += 32) {
      s16x8 af[4], bfr[2];
      #pragma unroll
      for (int m = 0; m < 4; ++m) {
        int row = wr * 64 + m * 16 + l15;
        af[m] = *(const s16x8*)((const char*)lds_a + row * 128 +
                                (((kk + lh * 8) * 2) ^ ((row & 7) << 4)));
      }
      #pragma unroll
      for (int q = 0; q < 2; ++q) {
        int row = wc * 32 + q * 16 + l15;
        bfr[q] = *(const s16x8*)((const char*)lds_b + row * 128 +
                                 (((kk + lh * 8) * 2) ^ ((row & 7) << 4)));
      }
      #pragma unroll
      for (int m = 0; m < 4; ++m)
        #pragma unroll
        for (int q = 0; q < 2; ++q)
          acc[m][q] = __builtin_amdgcn_mfma_f32_16x16x32_bf16(af[m], bfr[q], acc[m][q], 0, 0, 0);
    }
    __syncthreads();
  }
  #pragma unroll
  for (int m = 0; m < 4; ++m) {
    #pragma unroll
    for (int q = 0; q < 2; ++q) {
      int col = wc * 32 + q * 16 + l15;
      #pragma unroll
      for (int r = 0; r < 4; ++r) {
        int row = wr * 64 + m * 16 + lh * 4 + r;
        float v = acc[m][q][r] + bias[mt * 128 + row];
        *(bf16*)((char*)lds_a + row * 128 + ((col * 2) ^ ((row & 7) << 4))) =
            __float2bfloat16(v);
      }
    }
  }
  __syncthreads();
  #pragma unroll
  for (int it = 0; it < 4; ++it) {
    int g = tid + it * 256;            // 1024 granules of 16B: 128 rows x 8
    int row = g >> 3, cq = g & 7;
    int4 v = *(const int4*)((const char*)lds_a + row * 128 + ((cq * 16) ^ ((row & 7) << 4)));
    *(int4*)(D + ((size_t)n * 512 + mt * 128 + row) * 3136 + nt * 64 + cq * 8) = v;
  }
}

// ---- K2b: g-branch GEMM -> gg2[n][s][o][u16] (u innermost) ---------------
// M-tile = gathered rows: row_local r -> ts = (r>>2)*196 + sb*4 + (r&3)
// (16 u x 4 s). Epilogue lands in C-LDS [4 si][256 o][16 u], dump is linear.
__global__ __launch_bounds__(256) void gemm_g_kernel(
    const bf16* __restrict__ A,   // hG [8][3136][256]
    const bf16* __restrict__ W,   // pwG [2048][256]
    bf16* __restrict__ D,         // gg2 [8][196][2048][16]
    const float* __restrict__ bnscl, const float* __restrict__ bnsft) {
  int bid = blockIdx.x;
  int n = bid & 7, rem = bid >> 3;
  int otb = rem / 49, sb = rem % 49;
  __shared__ __align__(16) bf16 lds_a[64 * 64];    // 8 KB
  __shared__ __align__(16) bf16 lds_b[256 * 64];   // 32 KB; reused as C tile
  int tid = threadIdx.x;
  int wid = tid >> 6, lane = tid & 63;
  int l15 = lane & 15, lh = lane >> 4;
  f32x4 acc[4][4];
  #pragma unroll
  for (int m = 0; m < 4; ++m)
    #pragma unroll
    for (int q = 0; q < 4; ++q) acc[m][q] = (f32x4){0.f, 0.f, 0.f, 0.f};
  const bf16* Ab = A + (size_t)n * 3136 * 256;
  const bf16* Wb = W + (size_t)otb * 256 * 256;
  int arow = tid >> 3, ac16 = tid & 7;
  for (int k0 = 0; k0 < 256; k0 += 64) {
    #pragma unroll
    for (int it = 0; it < 2; ++it) {
      int row = arow + it * 32;                       // row_local 0..63
      int ts = (row >> 2) * 196 + sb * 4 + (row & 3); // gathered M row
      gload_lds16(Ab + (size_t)ts * 256 + k0 + ((ac16 ^ (row & 7)) * 8),
                  lds_a + (size_t)(row * 8 + ac16) * 8);
    }
    #pragma unroll
    for (int it = 0; it < 8; ++it) {
      int row = arow + it * 32;
      gload_lds16(Wb + (size_t)row * 256 + k0 + ((ac16 ^ (row & 7)) * 8),
                  lds_b + (size_t)(row * 8 + ac16) * 8);
    }
    __syncthreads();
    #pragma unroll
    for (int kk = 0; kk < 64; kk += 32) {
      s16x8 af[4], bfr[4];
      #pragma unroll
      for (int m = 0; m < 4; ++m) {
        int row = m * 16 + l15;
        af[m] = *(const s16x8*)((const char*)lds_a + row * 128 +
                                (((kk + lh * 8) * 2) ^ ((row & 7) << 4)));
      }
      #pragma unroll
      for (int q = 0; q < 4; ++q) {
        int row = wid * 64 + q * 16 + l15;
        bfr[q] = *(const s16x8*)((const char*)lds_b + row * 128 +
                                 (((kk + lh * 8) * 2) ^ ((row & 7) << 4)));
      }
      #pragma unroll
      for (int m = 0; m < 4; ++m)
        #pragma unroll
        for (int q = 0; q < 4; ++q)
          acc[m][q] = __builtin_amdgcn_mfma_f32_16x16x32_bf16(af[m], bfr[q], acc[m][q], 0, 0, 0);
    }
    __syncthreads();
  }
  // ---- epilogue: acc -> C-LDS [si][ocol][u] (linear, u innermost) --------
  #pragma unroll
  for (int q = 0; q < 4; ++q) {
    int ocol = wid * 64 + q * 16 + l15;
    float scl = bnscl[otb * 256 + ocol], sft = bnsft[otb * 256 + ocol];
    #pragma unroll
    for (int m = 0; m < 4; ++m) {
      #pragma unroll
      for (int r = 0; r < 4; ++r) {
        int row = m * 16 + lh * 4 + r;           // row_local
        int u = row >> 2, si = row & 3;
        float v = hswish_f(acc[m][q][r] * scl + sft);
        lds_b[(si * 256 + ocol) * 16 + u] = __float2bfloat16(v);
      }
    }
  }
  __syncthreads();
  #pragma unroll
  for (int it = 0; it < 8; ++it) {
    int g = tid + it * 256;            // 2048 granules of 16B, fully linear
    int si = g >> 9, remg = g & 511;
    size_t dst = ((size_t)n * 196 + sb * 4 + si) * (2048 * 16) +
                 (size_t)otb * 256 * 16 + (size_t)remg * 8;
    *(int4*)(D + dst) = *(const int4*)(lds_b + (size_t)g * 8);
  }
}

// ---- K3: adjacency logits, partial over e-blocks (atomicAdd) -------------
__global__ __launch_bounds__(256) void adj_accum_kernel(const bf16* __restrict__ th,
                                                        const bf16* __restrict__ ph,
                                                        float* __restrict__ adj_raw) {
  int bid = blockIdx.x;
  int eb = bid & 7, h = (bid >> 3) & 7, n = bid >> 6;
  __shared__ __align__(16) float As[16 * 196];
  __shared__ __align__(16) float Bs[16 * 196];
  int tid = threadIdx.x;
  int t = tid >> 4, u = tid & 15;
  float acc = 0.f;
  for (int e8 = 0; e8 < 8; ++e8) {
    int e = eb * 8 + e8;
    const bf16* tp = th + ((size_t)n * 512 + h * 64 + e) * 3136;
    const bf16* pp = ph + ((size_t)n * 512 + h * 64 + e) * 3136;
    __syncthreads();
    for (int i = tid; i < 3136; i += 256) {
      As[i] = __bfloat162float(tp[i]);
      Bs[i] = __bfloat162float(pp[i]);
    }
    __syncthreads();
    const float* ar = As + t * 196;
    const float* br = Bs + u * 196;
    #pragma unroll
    for (int j = 0; j < 49; ++j) {
      f32x4 a = *(const f32x4*)(ar + j * 4);
      f32x4 b = *(const f32x4*)(br + j * 4);
      acc = fmaf(a[0], b[0], acc); acc = fmaf(a[1], b[1], acc);
      acc = fmaf(a[2], b[2], acc); acc = fmaf(a[3], b[3], acc);
    }
  }
  atomicAdd(&adj_raw[((n * 8 + h) * 16 + t) * 16 + u], acc);
}

// ---- K3b: softmax over u (16), with FACTOR -------------------------------
__global__ void adj_softmax_kernel(const float* __restrict__ raw, float* __restrict__ adj) {
  int r = blockIdx.x * 256 + threadIdx.x;
  if (r >= 1024) return;
  const float* p = raw + r * 16;
  float* q = adj + r * 16;
  float v[16], mx = -1e30f;
  #pragma unroll
  for (int u = 0; u < 16; ++u) { v[u] = p[u] * kFACTOR; mx = fmaxf(mx, v[u]); }
  float s = 0.f;
  #pragma unroll
  for (int u = 0; u < 16; ++u) { v[u] = __expf(v[u] - mx); s += v[u]; }
  float inv = 1.f / s;
  #pragma unroll
  for (int u = 0; u < 16; ++u) q[u] = v[u] * inv;
}

// ---- K4/K6 unified consumer on gg2[n][s][o][u16] -------------------------
// block = (s, oh, n). Thread owns o' = oh*1024 + tid + k*256 -> h = tid&7.
// Per (tb,k): 2x16B loads give all 16 u for (s,o') -> 8x fewer load instrs.
// EPI=0: hf[n][t][h] += sum_{c'} hswish(z)        (shuffle over c-lanes)
// EPI=1: ztmp[n][ts][c] = sum_h attn*hswish(z)    (shuffle over h-lanes)
template <int EPI>
__global__ __launch_bounds__(256) void consume_kernel(
    const bf16* __restrict__ gg, const float* __restrict__ adj,
    const float* __restrict__ attn, float* __restrict__ hf,
    bf16* __restrict__ ztmp) {
  int s = blockIdx.x, oh = blockIdx.y, n = blockIdx.z;
  __shared__ __align__(16) float adjL[8][260];   // 8.3 KB; 260 pad -> 0-conflict
  __shared__ __align__(16) char aux[4096];       // zL (EPI=1) / hfp (EPI=0)
  bf16(*zL)[128] = (bf16(*)[128])aux;            // [16][128]
  float(*hfp)[8][16] = (float(*)[8][16])aux;     // [4][8][16]
  int tid = threadIdx.x;
  int h = tid & 7;
  for (int i = tid; i < 2048; i += 256) adjL[i >> 8][i & 255] = adj[n * 2048 + i];
  float atn[16];
  if (EPI == 1) {
    #pragma unroll
    for (int t = 0; t < 16; ++t) atn[t] = attn[n * 128 + t * 8 + h];
  }
  __syncthreads();
  const bf16* gbase = gg + (size_t)n * (3136 * 2048) + (size_t)s * (2048 * 16) +
                      (size_t)(oh * 1024 + tid) * 16;
  float hacc[16];
  if (EPI == 0) {
    #pragma unroll
    for (int t = 0; t < 16; ++t) hacc[t] = 0.f;
  }
  #pragma unroll
  for (int tb = 0; tb < 4; ++tb) {
    f32x4 aj[4][4];
    #pragma unroll
    for (int tt = 0; tt < 4; ++tt)
      #pragma unroll
      for (int u4 = 0; u4 < 4; ++u4)
        aj[tt][u4] = *(const f32x4*)&adjL[h][(tb * 4 + tt) * 16 + u4 * 4];
    #pragma unroll
    for (int k = 0; k < 4; ++k) {
      const bf16* gp = gbase + (size_t)k * (256 * 16);
      uint4 ra = *(const uint4*)gp;
      uint4 rb = *(const uint4*)(gp + 8);
      float gv[16];
      gv[0] = blo(ra.x); gv[1] = bhi(ra.x); gv[2] = blo(ra.y); gv[3] = bhi(ra.y);
      gv[4] = blo(ra.z); gv[5] = bhi(ra.z); gv[6] = blo(ra.w); gv[7] = bhi(ra.w);
      gv[8] = blo(rb.x); gv[9] = bhi(rb.x); gv[10] = blo(rb.y); gv[11] = bhi(rb.y);
      gv[12] = blo(rb.z); gv[13] = bhi(rb.z); gv[14] = blo(rb.w); gv[15] = bhi(rb.w);
      float zp[4];
      #pragma unroll
      for (int tt = 0; tt < 4; ++tt) {
        float z = 0.f;
        #pragma unroll
        for (int u4 = 0; u4 < 4; ++u4) {
          z = fmaf(aj[tt][u4][0], gv[u4 * 4 + 0], z);
          z = fmaf(aj[tt][u4][1], gv[u4 * 4 + 1], z);
          z = fmaf(aj[tt][u4][2], gv[u4 * 4 + 2], z);
          z = fmaf(aj[tt][u4][3], gv[u4 * 4 + 3], z);
        }
        if (EPI == 0) hacc[tb * 4 + tt] += hswish_f(z);
        else zp[tt] = atn[tb * 4 + tt] * hswish_f(z);
      }
      if (EPI == 1) {
        #pragma unroll
        for (int tt = 0; tt < 4; ++tt) {
          zp[tt] += __shfl_xor(zp[tt], 1);
          zp[tt] += __shfl_xor(zp[tt], 2);
          zp[tt] += __shfl_xor(zp[tt], 4);
        }
        if (h < 4)
          zL[tb * 4 + h][(tid >> 3) + k * 32] = __float2bfloat16(zp[h]);
      }
    }
  }
  if (EPI == 0) {
    #pragma unroll
    for (int t = 0; t < 16; ++t) {
      hacc[t] += __shfl_xor(hacc[t], 8);
      hacc[t] += __shfl_xor(hacc[t], 16);
      hacc[t] += __shfl_xor(hacc[t], 32);
    }
    if ((tid & 63) < 8) {
      #pragma unroll
      for (int t = 0; t < 16; ++t) hfp[tid >> 6][h][t] = hacc[t];
    }
    __syncthreads();
    if (tid < 128) {
      int h2 = tid & 7, t2 = tid >> 3;
      float v = hfp[0][h2][t2] + hfp[1][h2][t2] + hfp[2][h2][t2] + hfp[3][h2][t2];
      atomicAdd(&hf[n * 128 + t2 * 8 + h2], v);
    }
  } else {
    __syncthreads();
    int t = tid >> 4, cq = tid & 15;
    int4 v = *(const int4*)&zL[t][cq * 8];
    *(int4*)(ztmp + ((size_t)n * 3136 + t * 196 + s) * 256 + oh * 128 + cq * 8) = v;
  }
}

// ---- K5: head-mix attn = softmax(hf_mean @ heads_w) ----------------------
__global__ void attn_kernel(const float* __restrict__ hf, const float* __restrict__ hw,
                            float* __restrict__ attn) {
  int tid = threadIdx.x;
  if (tid >= 128) return;
  int n = tid >> 4, t = tid & 15;
  const float inv = 1.0f / (256.0f * 196.0f);
  float hm[8];
  #pragma unroll
  for (int h = 0; h < 8; ++h) hm[h] = hf[(n * 16 + t) * 8 + h] * inv;
  float o[8], mx = -1e30f;
  #pragma unroll
  for (int h2 = 0; h2 < 8; ++h2) {
    float s = 0.f;
    #pragma unroll
    for (int h = 0; h < 8; ++h) s = fmaf(hm[h], hw[h * 8 + h2], s);
    o[h2] = s; mx = fmaxf(mx, s);
  }
  float s = 0.f;
  #pragma unroll
  for (int h2 = 0; h2 < 8; ++h2) { o[h2] = __expf(o[h2] - mx); s += o[h2]; }
  float is = 1.f / s;
  #pragma unroll
  for (int h2 = 0; h2 < 8; ++h2) attn[(n * 16 + t) * 8 + h2] = o[h2] * is;
}

// ---- K7: transpose z [ts][c]->[c][ts], add residual, final hswish --------
__global__ __launch_bounds__(256) void zres_kernel(const bf16* __restrict__ ztmp,
                                                   const float* __restrict__ x,
                                                   float* __restrict__ out) {
  int tsb = blockIdx.x, cb = blockIdx.y, n = blockIdx.z;
  __shared__ __align__(16) bf16 tile[64 * 64];
  int tid = threadIdx.x;
  #pragma unroll
  for (int it = 0; it < 2; ++it) {
    int g = tid + it * 256;
    int row = g >> 3, cq = g & 7;
    int4 v = *(const int4*)(ztmp + ((size_t)n * 3136 + tsb * 64 + row) * 256 + cb * 64 + cq * 8);
    *(int4*)((char*)tile + row * 128 + ((cq * 16) ^ ((row & 7) << 4))) = v;
  }
  __syncthreads();
  int cl = tid & 63, tq = tid >> 6;
  size_t obase = ((size_t)(n * 256 + cb * 64 + cl)) * 3136 + tsb * 64 + tq * 16;
  #pragma unroll
  for (int i = 0; i < 16; i += 4) {
    f32x4 xv = *(const f32x4*)(x + obase + i);
    f32x4 r;
    #pragma unroll
    for (int j = 0; j < 4; ++j) {
      int row = tq * 16 + i + j;
      unsigned short zb = *(const unsigned short*)((const char*)tile + row * 128 +
                                                   ((cl * 2) ^ ((row & 7) << 4)));
      float z = __uint_as_float((unsigned)zb << 16);
      r[j] = hswish_f(xv[j] + z);
    }
    *(f32x4*)(out + obase + i) = r;
  }
}

}  // namespace

extern "C" void kernel_launch(void* const* d_in, const int* in_sizes, int n_in,
                              void* d_out, int out_size, void* d_ws, size_t ws_size,
                              hipStream_t stream) {
  const float* x       = (const float*)d_in[0];
  const float* t_dw    = (const float*)d_in[1];
  const float* t_g     = (const float*)d_in[2];
  const float* t_b     = (const float*)d_in[3];
  const float* t_m     = (const float*)d_in[4];
  const float* t_v     = (const float*)d_in[5];
  const float* t_pw    = (const float*)d_in[6];
  const float* p_dw    = (const float*)d_in[7];
  const float* p_g     = (const float*)d_in[8];
  const float* p_b     = (const float*)d_in[9];
  const float* p_m     = (const float*)d_in[10];
  const float* p_v     = (const float*)d_in[11];
  const float* p_pw    = (const float*)d_in[12];
  const float* g_dw    = (const float*)d_in[13];
  const float* g_g     = (const float*)d_in[14];
  const float* g_b     = (const float*)d_in[15];
  const float* g_m     = (const float*)d_in[16];
  const float* g_v     = (const float*)d_in[17];
  const float* g_pw    = (const float*)d_in[18];
  const float* t_pb    = (const float*)d_in[19];
  const float* p_pb    = (const float*)d_in[20];
  const float* g2_g    = (const float*)d_in[21];
  const float* g2_b    = (const float*)d_in[22];
  const float* g2_m    = (const float*)d_in[23];
  const float* g2_v    = (const float*)d_in[24];
  const float* heads_w = (const float*)d_in[25];
  float* out = (float*)d_out;
  (void)in_sizes; (void)n_in; (void)out_size; (void)ws_size;

  char* w = (char*)d_ws;
  size_t off = 0;
  auto take = [&](size_t bytes) {
    char* p = w + off;
    off = (off + bytes + 255) & ~(size_t)255;
    return p;
  };
  bf16* pwT = (bf16*)take(512 * 256 * 2);
  bf16* pwP = (bf16*)take(512 * 256 * 2);
  bf16* pwG = (bf16*)take(2048 * 256 * 2);
  float* bnscl = (float*)take(2048 * 4);
  float* bnsft = (float*)take(2048 * 4);
  bf16* hT  = (bf16*)take((size_t)8 * 3136 * 256 * 2);
  bf16* hP  = (bf16*)take((size_t)8 * 3136 * 256 * 2);
  bf16* hG  = (bf16*)take((size_t)8 * 3136 * 256 * 2);
  bf16* th  = (bf16*)take((size_t)8 * 512 * 3136 * 2);
  bf16* ph  = (bf16*)take((size_t)8 * 512 * 3136 * 2);
  bf16* gg  = (bf16*)take((size_t)8 * 3136 * 2048 * 2);  // gg2 [n][s][o][u16]
  float* adj_raw = (float*)take(1024 * 16 * 4);
  float* adj     = (float*)take(1024 * 16 * 4);
  float* hf      = (float*)take(1024 * 4);
  float* attn    = (float*)take(1024 * 4);
  bf16* ztmp = hT;  // hT dead after gemm_op theta

  hipMemsetAsync(adj_raw, 0, 1024 * 16 * 4, stream);
  hipMemsetAsync(hf, 0, 1024 * 4, stream);

  cvt_pw_kernel<<<2048, 256, 0, stream>>>(t_pw, p_pw, g_pw, g2_g, g2_b, g2_m, g2_v,
                                          pwT, pwP, pwG, bnscl, bnsft);
  conv_kernel<<<512, 256, 0, stream>>>(x, t_dw, t_g, t_b, t_m, t_v,
                                       p_dw, p_g, p_b, p_m, p_v,
                                       g_dw, g_g, g_b, g_m, g_v, hT, hP, hG);
  gemm_op_kernel<<<dim3(4, 49, 8), 256, 0, stream>>>(pwT, hT, th, t_pb);
  gemm_op_kernel<<<dim3(4, 49, 8), 256, 0, stream>>>(pwP, hP, ph, p_pb);
  gemm_g_kernel<<<3136, 256, 0, stream>>>(hG, pwG, gg, bnscl, bnsft);
  adj_accum_kernel<<<512, 256, 0, stream>>>(th, ph, adj_raw);
  adj_softmax_kernel<<<4, 256, 0, stream>>>(adj_raw, adj);
  consume_kernel<0><<<dim3(196, 2, 8), 256, 0, stream>>>(gg, adj, nullptr, hf, nullptr);
  attn_kernel<<<1, 128, 0, stream>>>(hf, heads_w, attn);
  consume_kernel<1><<<dim3(196, 2, 8), 256, 0, stream>>>(gg, adj, attn, nullptr, ztmp);
  zres_kernel<<<dim3(49, 4, 8), 256, 0, stream>>>(ztmp, x, out);
}